// Round 4
// baseline (602.321 us; speedup 1.0000x reference)
//
#include <hip/hip_runtime.h>

// ---------------------------------------------------------------------------
// PYG_GCN: y = relu(x@W_in+b_in) -> GCNConv(W_gcn,b_gcn) -> relu -> @W_cls+b_cls
// N=50000, E=600000, D=128, C=40.
// This round: coarse bucket sort (col>>7) + LDS fp32 accumulation per bucket.
// No memset, no N-wide scan, no random 4B global writes.
// ---------------------------------------------------------------------------

typedef __bf16 bf16x8 __attribute__((ext_vector_type(8)));
typedef float f32x4 __attribute__((ext_vector_type(4)));

#define NBUCK 512      // bucket = col>>7; used 0..390 for N=50000
#define CH_MAX 4704    // max edges per sort block (LDS capacity)

__device__ __forceinline__ ushort f2b(float f) {  // fp32 -> bf16 RNE
  uint u = __float_as_uint(f);
  return (ushort)((u + 0x7FFFu + ((u >> 16) & 1u)) >> 16);
}
__device__ __forceinline__ float b2f_lo(uint u) { return __uint_as_float(u << 16); }
__device__ __forceinline__ float b2f_hi(uint u) { return __uint_as_float(u & 0xFFFF0000u); }

// ---------------- prep: transpose+convert weights to bf16 col-major --------
__global__ __launch_bounds__(256) void k_prep(const float* __restrict__ Wi,
                                              const float* __restrict__ Wg,
                                              const float* __restrict__ Wc,
                                              ushort* __restrict__ Ti,
                                              ushort* __restrict__ Tg,
                                              ushort* __restrict__ Tc) {
  int idx = blockIdx.x * 256 + threadIdx.x;
  if (idx < 16384) {
    int c = idx >> 7, k = idx & 127;
    Ti[c * 128 + k] = f2b(Wi[k * 128 + c]);
  } else if (idx < 32768) {
    int j = idx - 16384;
    int c = j >> 7, k = j & 127;
    Tg[c * 128 + k] = f2b(Wg[k * 128 + c]);
  } else if (idx < 38912) {
    int j = idx - 32768;
    int c = j >> 7, k = j & 127;
    Tc[c * 128 + k] = (c < 40) ? f2b(Wc[k * 40 + c]) : (ushort)0;
  }
}

// ---------------- coarse histogram: H[bucket][block] -----------------------
__global__ __launch_bounds__(256) void k_chist(const int* __restrict__ col,
                                               int* __restrict__ H,
                                               int E, int chunk) {
  __shared__ int hist[NBUCK];
  const int tid = threadIdx.x;
  for (int b = tid; b < NBUCK; b += 256) hist[b] = 0;
  __syncthreads();
  const int e0 = blockIdx.x * chunk;
  const int cnt = min(chunk, E - e0);
  for (int i = tid; i < cnt; i += 256)
    atomicAdd(&hist[((unsigned)col[e0 + i]) >> 7], 1);
  __syncthreads();
  for (int b = tid; b < NBUCK; b += 256)
    H[b * gridDim.x + blockIdx.x] = hist[b];
}

// ---------------- exclusive scan (3-kernel, n multiple handled) ------------
__global__ __launch_bounds__(256) void k_scan1(int* __restrict__ P,
                                               int* __restrict__ aux, int n) {
  __shared__ int sd[256];
  const int tid = threadIdx.x;
  const int i0 = blockIdx.x * 1024 + tid * 4;
  int4 v = make_int4(0, 0, 0, 0);
  if (i0 + 3 < n) v = *(const int4*)&P[i0];
  else {
    if (i0 < n) v.x = P[i0];
    if (i0 + 1 < n) v.y = P[i0 + 1];
    if (i0 + 2 < n) v.z = P[i0 + 2];
  }
  const int s = v.x + v.y + v.z + v.w;
  sd[tid] = s;
  __syncthreads();
  for (int off = 1; off < 256; off <<= 1) {
    int u = (tid >= off) ? sd[tid - off] : 0;
    __syncthreads();
    sd[tid] += u;
    __syncthreads();
  }
  if (tid == 255) aux[blockIdx.x] = sd[255];
  const int excl = sd[tid] - s;
  int4 o;
  o.x = excl; o.y = o.x + v.x; o.z = o.y + v.y; o.w = o.z + v.z;
  if (i0 + 3 < n) *(int4*)&P[i0] = o;
  else {
    if (i0 < n) P[i0] = o.x;
    if (i0 + 1 < n) P[i0 + 1] = o.y;
    if (i0 + 2 < n) P[i0 + 2] = o.z;
  }
}

__global__ __launch_bounds__(64) void k_scan2(int* __restrict__ aux, int nblk) {
  const int lane = threadIdx.x;
  int v = (lane < nblk) ? aux[lane] : 0;
  int inc = v;
  for (int off = 1; off < 64; off <<= 1) {
    int u = __shfl_up(inc, off);
    if (lane >= off) inc += u;
  }
  if (lane < nblk) aux[lane] = inc - v;  // exclusive
}

__global__ __launch_bounds__(256) void k_scan3(int* __restrict__ P,
                                               const int* __restrict__ aux, int n) {
  const int i0 = blockIdx.x * 1024 + threadIdx.x * 4;
  const int a = aux[blockIdx.x];
  if (i0 + 3 < n) {
    int4 v = *(int4*)&P[i0];
    v.x += a; v.y += a; v.z += a; v.w += a;
    *(int4*)&P[i0] = v;
  } else {
    if (i0 < n) P[i0] += a;
    if (i0 + 1 < n) P[i0 + 1] += a;
    if (i0 + 2 < n) P[i0 + 2] += a;
  }
}

// ---------------- reorder: LDS-sort chunk by bucket, write ebuf ------------
// ebuf record: (c_local<<16) | row, c_local = col & 127, row < 65536.
__global__ __launch_bounds__(256) void k_reorder(const int* __restrict__ row,
                                                 const int* __restrict__ col,
                                                 const int* __restrict__ H,  // scanned
                                                 uint* __restrict__ ebuf,
                                                 int E, int chunk) {
  __shared__ int hist[NBUCK];
  __shared__ int lstart[NBUCK];
  __shared__ int cnt2[NBUCK];
  __shared__ int obase[NBUCK];
  __shared__ uint data[CH_MAX];
  __shared__ int gpos[CH_MAX];
  __shared__ int sd[256];
  const int tid = threadIdx.x;
  const int blk = blockIdx.x;
  for (int b = tid; b < NBUCK; b += 256) {
    hist[b] = 0; cnt2[b] = 0;
    obase[b] = H[b * gridDim.x + blk];
  }
  __syncthreads();
  const int e0 = blk * chunk;
  const int cnt = min(chunk, E - e0);
  for (int i = tid; i < cnt; i += 256)
    atomicAdd(&hist[((unsigned)col[e0 + i]) >> 7], 1);
  __syncthreads();
  // exclusive scan of hist[0..511] -> lstart (2 entries per thread)
  const int h0 = hist[2 * tid], h1 = hist[2 * tid + 1];
  const int ps = h0 + h1;
  sd[tid] = ps;
  __syncthreads();
  for (int off = 1; off < 256; off <<= 1) {
    int u = (tid >= off) ? sd[tid - off] : 0;
    __syncthreads();
    sd[tid] += u;
    __syncthreads();
  }
  const int ex = sd[tid] - ps;
  lstart[2 * tid] = ex;
  lstart[2 * tid + 1] = ex + h0;
  __syncthreads();
  for (int i = tid; i < cnt; i += 256) {
    const int c = col[e0 + i], r = row[e0 + i];
    const int b = ((unsigned)c) >> 7;
    const int rk = atomicAdd(&cnt2[b], 1);
    const int slot = lstart[b] + rk;
    data[slot] = ((uint)(c & 127) << 16) | (uint)r;
    gpos[slot] = obase[b] + rk;
  }
  __syncthreads();
  for (int i = tid; i < cnt; i += 256)
    ebuf[gpos[i]] = data[i];
}

// ---------------- per-bucket degree -> dinv (coalesced, no memset) ---------
__global__ __launch_bounds__(256) void k_degdinv(const uint* __restrict__ ebuf,
                                                 const int* __restrict__ H,
                                                 float* __restrict__ dinv,
                                                 int sortb, int n) {
  __shared__ int cnt[128];
  const int tid = threadIdx.x;
  if (tid < 128) cnt[tid] = 0;
  __syncthreads();
  const int b = blockIdx.x;
  const int start = H[b * sortb];
  const int end = H[(b + 1) * sortb];
  for (int i = start + tid; i < end; i += 256)
    atomicAdd(&cnt[ebuf[i] >> 16], 1);
  __syncthreads();
  if (tid < 128) {
    const int node = b * 128 + tid;
    if (node < n) dinv[node] = rsqrtf((float)cnt[tid] + 1.0f);
  }
}

// ---------------------------------------------------------------------------
// MFMA GEMM, 64 rows/block, 128 cols, K=128. Wt bf16 col-major [128][128].
// ---------------------------------------------------------------------------
template<bool RELU, bool BIAS, bool ABF16>
__global__ __launch_bounds__(256) void k_gemm_mfma(const void* __restrict__ Ap,
                                                   const ushort* __restrict__ Wt,
                                                   const float* __restrict__ bias,
                                                   ushort* __restrict__ O, int nrows) {
  __shared__ ushort As[64][136];
  __shared__ ushort Bs[128][136];
  const int tid = threadIdx.x;
  const int row0 = blockIdx.x * 64;

#pragma unroll
  for (int q = 0; q < 8; ++q) {
    int f = tid + 256 * q;
    int r = f >> 4, cw = f & 15;
    *(uint4*)&Bs[r][cw * 8] = *(const uint4*)&Wt[r * 128 + cw * 8];
  }
  if (ABF16) {
    const ushort* A = (const ushort*)Ap;
#pragma unroll
    for (int q = 0; q < 4; ++q) {
      int f = tid + 256 * q;
      int r = f >> 4, cw = f & 15;
      uint4 v = make_uint4(0u, 0u, 0u, 0u);
      if (row0 + r < nrows) v = *(const uint4*)&A[(size_t)(row0 + r) * 128 + cw * 8];
      *(uint4*)&As[r][cw * 8] = v;
    }
  } else {
    const float* A = (const float*)Ap;
#pragma unroll
    for (int q = 0; q < 8; ++q) {
      int f = tid + 256 * q;
      int r = f >> 5, kc = f & 31;
      float4 v = make_float4(0.f, 0.f, 0.f, 0.f);
      if (row0 + r < nrows) v = *(const float4*)&A[(size_t)(row0 + r) * 128 + kc * 4];
      ushort4 o;
      o.x = f2b(v.x); o.y = f2b(v.y); o.z = f2b(v.z); o.w = f2b(v.w);
      *(ushort4*)&As[r][kc * 4] = o;
    }
  }
  __syncthreads();

  const int wid = tid >> 6, lane = tid & 63;
  const int fr = lane & 15;
  const int fg = lane >> 4;

  f32x4 acc[8];
#pragma unroll
  for (int n = 0; n < 8; ++n) acc[n] = (f32x4){0.f, 0.f, 0.f, 0.f};

#pragma unroll
  for (int ks = 0; ks < 4; ++ks) {
    const int kb = ks * 32 + fg * 8;
    bf16x8 a = *(const bf16x8*)&As[wid * 16 + fr][kb];
#pragma unroll
    for (int n = 0; n < 8; ++n) {
      bf16x8 b = *(const bf16x8*)&Bs[n * 16 + fr][kb];
      acc[n] = __builtin_amdgcn_mfma_f32_16x16x32_bf16(a, b, acc[n], 0, 0, 0);
    }
  }

  const int r0 = row0 + wid * 16 + fg * 4;
#pragma unroll
  for (int n = 0; n < 8; ++n) {
    const int cn = n * 16 + fr;
    const float bv = BIAS ? bias[cn] : 0.f;
#pragma unroll
    for (int i = 0; i < 4; ++i) {
      const int rr = r0 + i;
      if (rr < nrows) {
        float v = acc[n][i] + bv;
        if (RELU) v = fmaxf(v, 0.f);
        O[(size_t)rr * 128 + cn] = f2b(v);
      }
    }
  }
}

// ---------------------------------------------------------------------------
// Bucket aggregation: 64KB LDS fp32 acc [128 nodes][128 cols].
// t[c] = relu(dinv[c]*(sum_e dinv[r]*xw[r] + dinv[c]*xw[c]) + b_gcn)
// ---------------------------------------------------------------------------
__global__ __launch_bounds__(512) void k_aggB(const uint* __restrict__ ebuf,
                                              const int* __restrict__ H,
                                              const ushort* __restrict__ xws,
                                              const float* __restrict__ dinv,
                                              const float* __restrict__ b_gcn,
                                              ushort* __restrict__ t,
                                              int sortb, int n) {
  __shared__ float acc[128 * 128];  // 64 KB
  const int tid = threadIdx.x;
#pragma unroll
  for (int q = 0; q < 8; ++q)
    *(f32x4*)&acc[(tid + q * 512) * 4] = (f32x4){0.f, 0.f, 0.f, 0.f};
  __syncthreads();

  const int b = blockIdx.x;
  const int start = H[b * sortb];
  const int end = H[(b + 1) * sortb];
  const int len = end - start;
  const int wave = tid >> 6, lane = tid & 63;
  const int ws_ = start + (int)(((long long)len * wave) >> 3);
  const int we_ = start + (int)(((long long)len * (wave + 1)) >> 3);

  int e = ws_;
  for (; e + 1 < we_; e += 2) {
    const uint v0 = ebuf[e], v1 = ebuf[e + 1];
    const int r0 = v0 & 0xFFFF, r1 = v1 & 0xFFFF;
    const float d0 = dinv[r0], d1 = dinv[r1];
    const uint u0 = *(const uint*)&xws[(size_t)r0 * 128 + lane * 2];
    const uint u1 = *(const uint*)&xws[(size_t)r1 * 128 + lane * 2];
    const int c0 = v0 >> 16, c1 = v1 >> 16;
    atomicAdd(&acc[c0 * 128 + lane * 2],     b2f_lo(u0) * d0);
    atomicAdd(&acc[c0 * 128 + lane * 2 + 1], b2f_hi(u0) * d0);
    atomicAdd(&acc[c1 * 128 + lane * 2],     b2f_lo(u1) * d1);
    atomicAdd(&acc[c1 * 128 + lane * 2 + 1], b2f_hi(u1) * d1);
  }
  if (e < we_) {
    const uint v = ebuf[e];
    const int r = v & 0xFFFF;
    const float d = dinv[r];
    const uint u = *(const uint*)&xws[(size_t)r * 128 + lane * 2];
    const int c = v >> 16;
    atomicAdd(&acc[c * 128 + lane * 2],     b2f_lo(u) * d);
    atomicAdd(&acc[c * 128 + lane * 2 + 1], b2f_hi(u) * d);
  }
  __syncthreads();

  // finalize: 128 nodes x 32 float4 groups
#pragma unroll
  for (int q = 0; q < 8; ++q) {
    const int j = tid + q * 512;
    const int nl = j >> 5;
    const int c4 = (j & 31) * 4;
    const int node = b * 128 + nl;
    if (node < n) {
      const float dc = dinv[node];
      f32x4 a = *(f32x4*)&acc[nl * 128 + c4];
      const uint2 su = *(const uint2*)&xws[(size_t)node * 128 + c4];
      const float s0 = b2f_lo(su.x), s1 = b2f_hi(su.x);
      const float s2 = b2f_lo(su.y), s3 = b2f_hi(su.y);
      const float4 bg = *(const float4*)&b_gcn[c4];
      ushort4 o;
      o.x = f2b(fmaxf((a[0] + dc * s0) * dc + bg.x, 0.f));
      o.y = f2b(fmaxf((a[1] + dc * s1) * dc + bg.y, 0.f));
      o.z = f2b(fmaxf((a[2] + dc * s2) * dc + bg.z, 0.f));
      o.w = f2b(fmaxf((a[3] + dc * s3) * dc + bg.w, 0.f));
      *(ushort4*)&t[(size_t)node * 128 + c4] = o;
    }
  }
}

// ---------------------------------------------------------------------------
// Output layer MFMA: out[fp32] = t[bf16] @ W_cls + b_cls. N padded 40->48.
// ---------------------------------------------------------------------------
__global__ __launch_bounds__(256) void k_out_mfma(const ushort* __restrict__ t,
                                                  const ushort* __restrict__ Wtc,
                                                  const float* __restrict__ bc,
                                                  float* __restrict__ out, int nrows) {
  __shared__ ushort As[64][136];
  __shared__ ushort Bs[48][136];
  const int tid = threadIdx.x;
  const int row0 = blockIdx.x * 64;

#pragma unroll
  for (int q = 0; q < 3; ++q) {
    int f = tid + 256 * q;
    int r = f >> 4, cw = f & 15;
    *(uint4*)&Bs[r][cw * 8] = *(const uint4*)&Wtc[r * 128 + cw * 8];
  }
#pragma unroll
  for (int q = 0; q < 4; ++q) {
    int f = tid + 256 * q;
    int r = f >> 4, cw = f & 15;
    uint4 v = make_uint4(0u, 0u, 0u, 0u);
    if (row0 + r < nrows) v = *(const uint4*)&t[(size_t)(row0 + r) * 128 + cw * 8];
    *(uint4*)&As[r][cw * 8] = v;
  }
  __syncthreads();

  const int wid = tid >> 6, lane = tid & 63;
  const int fr = lane & 15, fg = lane >> 4;

  f32x4 acc[3];
#pragma unroll
  for (int n = 0; n < 3; ++n) acc[n] = (f32x4){0.f, 0.f, 0.f, 0.f};

#pragma unroll
  for (int ks = 0; ks < 4; ++ks) {
    const int kb = ks * 32 + fg * 8;
    bf16x8 a = *(const bf16x8*)&As[wid * 16 + fr][kb];
#pragma unroll
    for (int n = 0; n < 3; ++n) {
      bf16x8 b = *(const bf16x8*)&Bs[n * 16 + fr][kb];
      acc[n] = __builtin_amdgcn_mfma_f32_16x16x32_bf16(a, b, acc[n], 0, 0, 0);
    }
  }

  const int r0 = row0 + wid * 16 + fg * 4;
#pragma unroll
  for (int n = 0; n < 3; ++n) {
    const int cn = n * 16 + fr;
    if (cn < 40) {
      const float bv = bc[cn];
#pragma unroll
      for (int i = 0; i < 4; ++i) {
        const int rr = r0 + i;
        if (rr < nrows) out[(size_t)rr * 40 + cn] = acc[n][i] + bv;
      }
    }
  }
}

extern "C" void kernel_launch(void* const* d_in, const int* in_sizes, int n_in,
                              void* d_out, int out_size, void* d_ws, size_t ws_size,
                              hipStream_t stream) {
  const float* x     = (const float*)d_in[0];
  const int*   ei    = (const int*)d_in[1];
  const float* W_in  = (const float*)d_in[2];
  const float* b_in  = (const float*)d_in[3];
  const float* W_gcn = (const float*)d_in[4];
  const float* b_gcn = (const float*)d_in[5];
  const float* W_cls = (const float*)d_in[6];
  const float* b_cls = (const float*)d_in[7];
  float* out = (float*)d_out;

  const int N = in_sizes[0] / 128;
  const int E = in_sizes[1] / 2;
  const int* row = ei;
  const int* col = ei + E;

  const int sortb = (E + CH_MAX - 1) / CH_MAX;       // 128 for E=600000
  const int chunk = (E + sortb - 1) / sortb;          // <= CH_MAX
  const int nscan = NBUCK * sortb;                    // 65536
  const int nblk  = (nscan + 1023) / 1024;            // 64
  const int nbuck = (N + 127) >> 7;                   // 391

  // d_ws: h bf16 (N*128), xws bf16 (N*128), Wt buffers
  ushort* h   = (ushort*)d_ws;
  ushort* xws = h + (size_t)N * 128;
  ushort* Wti = xws + (size_t)N * 128;
  ushort* Wtg = Wti + 128 * 128;
  ushort* Wtc = Wtg + 128 * 128;                      // 48 x 128 zero-padded
  // scratch parked in d_out (fully overwritten by k_out_mfma at the end):
  uint*  ebuf = (uint*)d_out;                         // E uints
  int*   H    = (int*)d_out + E;                      // nscan ints
  int*   aux  = H + nscan;                            // nblk ints
  float* dinv = (float*)(aux + nblk);                 // N floats

  k_prep<<<152, 256, 0, stream>>>(W_in, W_gcn, W_cls, Wti, Wtg, Wtc);

  // coarse bucket sort of edges by col>>7
  k_chist<<<sortb, 256, 0, stream>>>(col, H, E, chunk);
  k_scan1<<<nblk, 256, 0, stream>>>(H, aux, nscan);
  k_scan2<<<1, 64, 0, stream>>>(aux, nblk);
  k_scan3<<<nblk, 256, 0, stream>>>(H, aux, nscan);
  k_reorder<<<sortb, 256, 0, stream>>>(row, col, H, ebuf, E, chunk);
  k_degdinv<<<nbuck, 256, 0, stream>>>(ebuf, H, dinv, sortb, N);

  // h = relu(x @ W_in + b_in)
  k_gemm_mfma<true, true, false>
      <<<(N + 63) / 64, 256, 0, stream>>>(x, Wti, b_in, h, N);

  // xws = h @ W_gcn   (raw; dinv applied per-edge in k_aggB)
  k_gemm_mfma<false, false, true>
      <<<(N + 63) / 64, 256, 0, stream>>>(h, Wtg, nullptr, xws, N);

  // t = relu(dinv[c]*(sum dinv[r]*xw[r] + dinv[c]*xw[c]) + b_gcn) -> h
  k_aggB<<<nbuck, 512, 0, stream>>>(ebuf, H, xws, dinv, b_gcn, h, sortb, N);

  // out = t @ W_cls + b_cls
  k_out_mfma<<<(N + 63) / 64, 256, 0, stream>>>(h, Wtc, b_cls, out, N);
}

// Round 6
// 118.199 us; speedup vs baseline: 5.0958x; 5.0958x over previous
//
#include <hip/hip_runtime.h>

// ---------------------------------------------------------------------------
// PYG_GCN: y = relu(x@W_in+b_in) -> GCNConv(W_gcn,b_gcn) -> relu -> @W_cls+b_cls
// N=50000, E=600000, D=128, C=40.
// R5 resubmit (infra failure last round): R3 structure (per-node CSR +
// wave-per-node gather) minus the two 45us losers: no memset (LDS-zeroed
// counters), no random-4B k_place (two-level bucket sort; final scatter
// confined to per-bucket 6KB windows).
// ---------------------------------------------------------------------------

typedef __bf16 bf16x8 __attribute__((ext_vector_type(8)));
typedef float f32x4 __attribute__((ext_vector_type(4)));

#define NBUCK 512      // bucket = col>>7; used 0..390 for N=50000
#define CH_MAX 4704    // max edges per sort-chunk block

__device__ __forceinline__ ushort f2b(float f) {  // fp32 -> bf16 RNE
  uint u = __float_as_uint(f);
  return (ushort)((u + 0x7FFFu + ((u >> 16) & 1u)) >> 16);
}
__device__ __forceinline__ float b2f_lo(uint u) { return __uint_as_float(u << 16); }
__device__ __forceinline__ float b2f_hi(uint u) { return __uint_as_float(u & 0xFFFF0000u); }

// ---------------- prep: transpose+convert weights to bf16 col-major --------
__global__ __launch_bounds__(256) void k_prep(const float* __restrict__ Wi,
                                              const float* __restrict__ Wg,
                                              const float* __restrict__ Wc,
                                              ushort* __restrict__ Ti,
                                              ushort* __restrict__ Tg,
                                              ushort* __restrict__ Tc) {
  int idx = blockIdx.x * 256 + threadIdx.x;
  if (idx < 16384) {
    int c = idx >> 7, k = idx & 127;
    Ti[c * 128 + k] = f2b(Wi[k * 128 + c]);
  } else if (idx < 32768) {
    int j = idx - 16384;
    int c = j >> 7, k = j & 127;
    Tg[c * 128 + k] = f2b(Wg[k * 128 + c]);
  } else if (idx < 38912) {
    int j = idx - 32768;
    int c = j >> 7, k = j & 127;
    Tc[c * 128 + k] = (c < 40) ? f2b(Wc[k * 40 + c]) : (ushort)0;
  }
}

// ---------------- coarse histogram: H[bucket][block] -----------------------
__global__ __launch_bounds__(256) void k_chist(const int* __restrict__ col,
                                               int* __restrict__ H,
                                               int E, int chunk) {
  __shared__ int hist[NBUCK];
  const int tid = threadIdx.x;
  for (int b = tid; b < NBUCK; b += 256) hist[b] = 0;
  __syncthreads();
  const int e0 = blockIdx.x * chunk;
  const int cnt = min(chunk, E - e0);
  for (int i = tid; i < cnt; i += 256)
    atomicAdd(&hist[((unsigned)col[e0 + i]) >> 7], 1);
  __syncthreads();
  for (int b = tid; b < NBUCK; b += 256)
    H[b * gridDim.x + blockIdx.x] = hist[b];
}

// ---------------- exclusive scan (3-kernel) --------------------------------
__global__ __launch_bounds__(256) void k_scan1(int* __restrict__ P,
                                               int* __restrict__ aux, int n) {
  __shared__ int sd[256];
  const int tid = threadIdx.x;
  const int i0 = blockIdx.x * 1024 + tid * 4;
  int4 v = make_int4(0, 0, 0, 0);
  if (i0 + 3 < n) v = *(const int4*)&P[i0];
  else {
    if (i0 < n) v.x = P[i0];
    if (i0 + 1 < n) v.y = P[i0 + 1];
    if (i0 + 2 < n) v.z = P[i0 + 2];
  }
  const int s = v.x + v.y + v.z + v.w;
  sd[tid] = s;
  __syncthreads();
  for (int off = 1; off < 256; off <<= 1) {
    int u = (tid >= off) ? sd[tid - off] : 0;
    __syncthreads();
    sd[tid] += u;
    __syncthreads();
  }
  if (tid == 255) aux[blockIdx.x] = sd[255];
  const int excl = sd[tid] - s;
  int4 o;
  o.x = excl; o.y = o.x + v.x; o.z = o.y + v.y; o.w = o.z + v.z;
  if (i0 + 3 < n) *(int4*)&P[i0] = o;
  else {
    if (i0 < n) P[i0] = o.x;
    if (i0 + 1 < n) P[i0 + 1] = o.y;
    if (i0 + 2 < n) P[i0 + 2] = o.z;
  }
}

__global__ __launch_bounds__(64) void k_scan2(int* __restrict__ aux, int nblk) {
  const int lane = threadIdx.x;
  int v = (lane < nblk) ? aux[lane] : 0;
  int inc = v;
  for (int off = 1; off < 64; off <<= 1) {
    int u = __shfl_up(inc, off);
    if (lane >= off) inc += u;
  }
  if (lane < nblk) aux[lane] = inc - v;  // exclusive
}

__global__ __launch_bounds__(256) void k_scan3(int* __restrict__ P,
                                               const int* __restrict__ aux, int n) {
  const int i0 = blockIdx.x * 1024 + threadIdx.x * 4;
  const int a = aux[blockIdx.x];
  if (i0 + 3 < n) {
    int4 v = *(int4*)&P[i0];
    v.x += a; v.y += a; v.z += a; v.w += a;
    *(int4*)&P[i0] = v;
  } else {
    if (i0 < n) P[i0] += a;
    if (i0 + 1 < n) P[i0 + 1] += a;
    if (i0 + 2 < n) P[i0 + 2] += a;
  }
}

// ---------------- reorder: LDS-sort chunk by bucket, write ebuf ------------
// ebuf record: (c_local<<16) | row  (row < 65536 since N=50000).
__global__ __launch_bounds__(256) void k_reorder(const int* __restrict__ row,
                                                 const int* __restrict__ col,
                                                 const int* __restrict__ H,  // scanned
                                                 uint* __restrict__ ebuf,
                                                 int E, int chunk) {
  __shared__ int hist[NBUCK];
  __shared__ int lstart[NBUCK];
  __shared__ int cnt2[NBUCK];
  __shared__ int obase[NBUCK];
  __shared__ uint data[CH_MAX];
  __shared__ int gpos[CH_MAX];
  __shared__ int sd[256];
  const int tid = threadIdx.x;
  const int blk = blockIdx.x;
  for (int b = tid; b < NBUCK; b += 256) {
    hist[b] = 0; cnt2[b] = 0;
    obase[b] = H[b * gridDim.x + blk];
  }
  __syncthreads();
  const int e0 = blk * chunk;
  const int cnt = min(chunk, E - e0);
  for (int i = tid; i < cnt; i += 256)
    atomicAdd(&hist[((unsigned)col[e0 + i]) >> 7], 1);
  __syncthreads();
  const int h0 = hist[2 * tid], h1 = hist[2 * tid + 1];
  const int ps = h0 + h1;
  sd[tid] = ps;
  __syncthreads();
  for (int off = 1; off < 256; off <<= 1) {
    int u = (tid >= off) ? sd[tid - off] : 0;
    __syncthreads();
    sd[tid] += u;
    __syncthreads();
  }
  const int ex = sd[tid] - ps;
  lstart[2 * tid] = ex;
  lstart[2 * tid + 1] = ex + h0;
  __syncthreads();
  for (int i = tid; i < cnt; i += 256) {
    const int c = col[e0 + i], r = row[e0 + i];
    const int b = ((unsigned)c) >> 7;
    const int rk = atomicAdd(&cnt2[b], 1);
    const int slot = lstart[b] + rk;
    data[slot] = ((uint)(c & 127) << 16) | (uint)r;
    gpos[slot] = obase[b] + rk;
  }
  __syncthreads();
  for (int i = tid; i < cnt; i += 256)
    ebuf[gpos[i]] = data[i];
}

// ---------------- per-bucket fine sort -> srcrow CSR + P + dinv ------------
// One block per 128-node bucket. Scatter writes confined to the bucket's
// private window [start,end) of srcrow -> no cross-XCD line ping-pong.
// P[node] = END offset of node's segment (R3 convention: seg = [P[c-1],P[c])).
__global__ __launch_bounds__(256) void k_sort2(const uint* __restrict__ ebuf,
                                               const int* __restrict__ H,
                                               int* __restrict__ srcrow,
                                               int* __restrict__ P,
                                               float* __restrict__ dinv,
                                               int sortb, int n) {
  __shared__ int cnt[128];
  __shared__ int lstart[128];
  __shared__ int cnt2[128];
  __shared__ int sd[256];
  const int tid = threadIdx.x;
  if (tid < 128) { cnt[tid] = 0; cnt2[tid] = 0; }
  __syncthreads();
  const int b = blockIdx.x;
  const int start = H[b * sortb];
  const int end = H[(b + 1) * sortb];
  for (int i = start + tid; i < end; i += 256)
    atomicAdd(&cnt[ebuf[i] >> 16], 1);
  __syncthreads();
  const int cv = (tid < 128) ? cnt[tid] : 0;
  sd[tid] = cv;
  __syncthreads();
  for (int off = 1; off < 256; off <<= 1) {
    int u = (tid >= off) ? sd[tid - off] : 0;
    __syncthreads();
    sd[tid] += u;
    __syncthreads();
  }
  if (tid < 128) {
    const int ex = sd[tid] - cv;  // exclusive scan of cnt
    lstart[tid] = ex;
    const int node = b * 128 + tid;
    if (node < n) {
      P[node] = start + ex + cv;            // end offset
      dinv[node] = rsqrtf((float)cv + 1.0f);
    }
  }
  __syncthreads();
  for (int i = start + tid; i < end; i += 256) {
    const uint v = ebuf[i];
    const int c = v >> 16;
    const int rk = atomicAdd(&cnt2[c], 1);
    srcrow[start + lstart[c] + rk] = (int)(v & 0xFFFFu);
  }
}

// ---------------------------------------------------------------------------
// MFMA GEMM, 64 rows/block, 128 cols, K=128. Wt bf16 col-major [128][128].
// O(bf16) = post(A@W): +bias, relu, *scale[row]. LDS rows padded to 136.
// ---------------------------------------------------------------------------
template<bool RELU, bool BIAS, bool SCALE, bool ABF16>
__global__ __launch_bounds__(256) void k_gemm_mfma(const void* __restrict__ Ap,
                                                   const ushort* __restrict__ Wt,
                                                   const float* __restrict__ bias,
                                                   const float* __restrict__ scale,
                                                   ushort* __restrict__ O, int nrows) {
  __shared__ ushort As[64][136];
  __shared__ ushort Bs[128][136];
  const int tid = threadIdx.x;
  const int row0 = blockIdx.x * 64;

#pragma unroll
  for (int q = 0; q < 8; ++q) {
    int f = tid + 256 * q;
    int r = f >> 4, cw = f & 15;
    *(uint4*)&Bs[r][cw * 8] = *(const uint4*)&Wt[r * 128 + cw * 8];
  }
  if (ABF16) {
    const ushort* A = (const ushort*)Ap;
#pragma unroll
    for (int q = 0; q < 4; ++q) {
      int f = tid + 256 * q;
      int r = f >> 4, cw = f & 15;
      uint4 v = make_uint4(0u, 0u, 0u, 0u);
      if (row0 + r < nrows) v = *(const uint4*)&A[(size_t)(row0 + r) * 128 + cw * 8];
      *(uint4*)&As[r][cw * 8] = v;
    }
  } else {
    const float* A = (const float*)Ap;
#pragma unroll
    for (int q = 0; q < 8; ++q) {
      int f = tid + 256 * q;
      int r = f >> 5, kc = f & 31;
      float4 v = make_float4(0.f, 0.f, 0.f, 0.f);
      if (row0 + r < nrows) v = *(const float4*)&A[(size_t)(row0 + r) * 128 + kc * 4];
      ushort4 o;
      o.x = f2b(v.x); o.y = f2b(v.y); o.z = f2b(v.z); o.w = f2b(v.w);
      *(ushort4*)&As[r][kc * 4] = o;
    }
  }
  __syncthreads();

  const int wid = tid >> 6, lane = tid & 63;
  const int fr = lane & 15;
  const int fg = lane >> 4;

  f32x4 acc[8];
#pragma unroll
  for (int n = 0; n < 8; ++n) acc[n] = (f32x4){0.f, 0.f, 0.f, 0.f};

#pragma unroll
  for (int ks = 0; ks < 4; ++ks) {
    const int kb = ks * 32 + fg * 8;
    bf16x8 a = *(const bf16x8*)&As[wid * 16 + fr][kb];
#pragma unroll
    for (int n = 0; n < 8; ++n) {
      bf16x8 b = *(const bf16x8*)&Bs[n * 16 + fr][kb];
      acc[n] = __builtin_amdgcn_mfma_f32_16x16x32_bf16(a, b, acc[n], 0, 0, 0);
    }
  }

  const int r0 = row0 + wid * 16 + fg * 4;
#pragma unroll
  for (int n = 0; n < 8; ++n) {
    const int cn = n * 16 + fr;
    const float bv = BIAS ? bias[cn] : 0.f;
#pragma unroll
    for (int i = 0; i < 4; ++i) {
      const int rr = r0 + i;
      if (rr < nrows) {
        float v = acc[n][i] + bv;
        if (RELU) v = fmaxf(v, 0.f);
        if (SCALE) v *= scale[rr];
        O[(size_t)rr * 128 + cn] = f2b(v);
      }
    }
  }
}

// ---------------------------------------------------------------------------
// Aggregate (bf16 gather): t[c] = relu(dinv[c]*(sum xws[r] + xws[c]) + b_gcn)
// One wave per node; lane owns cols {2*lane, 2*lane+1}. xws pre-scaled by
// dinv[r] in GEMM2 epilogue.
// ---------------------------------------------------------------------------
__global__ __launch_bounds__(256) void k_agg(const int* __restrict__ P,
                                             const int* __restrict__ srcrow,
                                             const ushort* __restrict__ xws,
                                             const float* __restrict__ dinv,
                                             const float* __restrict__ b_gcn,
                                             ushort* __restrict__ t, int n) {
  const int c = blockIdx.x * 4 + (threadIdx.x >> 6);
  if (c >= n) return;
  const int lane = threadIdx.x & 63;
  const int begin = (c == 0) ? 0 : P[c - 1];
  const int end = P[c];
  const size_t off = (size_t)lane * 2;

  uint s = *(const uint*)&xws[(size_t)c * 128 + off];  // self term
  float ax = b2f_lo(s), ay = b2f_hi(s);
  int e = begin;
  for (; e + 4 <= end; e += 4) {
    int r0 = srcrow[e], r1 = srcrow[e + 1], r2 = srcrow[e + 2], r3 = srcrow[e + 3];
    uint v0 = *(const uint*)&xws[(size_t)r0 * 128 + off];
    uint v1 = *(const uint*)&xws[(size_t)r1 * 128 + off];
    uint v2 = *(const uint*)&xws[(size_t)r2 * 128 + off];
    uint v3 = *(const uint*)&xws[(size_t)r3 * 128 + off];
    ax += (b2f_lo(v0) + b2f_lo(v1)) + (b2f_lo(v2) + b2f_lo(v3));
    ay += (b2f_hi(v0) + b2f_hi(v1)) + (b2f_hi(v2) + b2f_hi(v3));
  }
  for (; e < end; ++e) {
    uint v = *(const uint*)&xws[(size_t)srcrow[e] * 128 + off];
    ax += b2f_lo(v);
    ay += b2f_hi(v);
  }
  const float dc = dinv[c];
  const float2 b = *(const float2*)&b_gcn[lane * 2];
  ushort2 o;
  o.x = f2b(fmaxf(fmaf(dc, ax, b.x), 0.f));
  o.y = f2b(fmaxf(fmaf(dc, ay, b.y), 0.f));
  *(ushort2*)&t[(size_t)c * 128 + off] = o;
}

// ---------------------------------------------------------------------------
// Output layer MFMA: out[fp32] = t[bf16] @ W_cls + b_cls. N padded 40->48.
// ---------------------------------------------------------------------------
__global__ __launch_bounds__(256) void k_out_mfma(const ushort* __restrict__ t,
                                                  const ushort* __restrict__ Wtc,
                                                  const float* __restrict__ bc,
                                                  float* __restrict__ out, int nrows) {
  __shared__ ushort As[64][136];
  __shared__ ushort Bs[48][136];
  const int tid = threadIdx.x;
  const int row0 = blockIdx.x * 64;

#pragma unroll
  for (int q = 0; q < 3; ++q) {
    int f = tid + 256 * q;
    int r = f >> 4, cw = f & 15;
    *(uint4*)&Bs[r][cw * 8] = *(const uint4*)&Wtc[r * 128 + cw * 8];
  }
#pragma unroll
  for (int q = 0; q < 4; ++q) {
    int f = tid + 256 * q;
    int r = f >> 4, cw = f & 15;
    uint4 v = make_uint4(0u, 0u, 0u, 0u);
    if (row0 + r < nrows) v = *(const uint4*)&t[(size_t)(row0 + r) * 128 + cw * 8];
    *(uint4*)&As[r][cw * 8] = v;
  }
  __syncthreads();

  const int wid = tid >> 6, lane = tid & 63;
  const int fr = lane & 15, fg = lane >> 4;

  f32x4 acc[3];
#pragma unroll
  for (int n = 0; n < 3; ++n) acc[n] = (f32x4){0.f, 0.f, 0.f, 0.f};

#pragma unroll
  for (int ks = 0; ks < 4; ++ks) {
    const int kb = ks * 32 + fg * 8;
    bf16x8 a = *(const bf16x8*)&As[wid * 16 + fr][kb];
#pragma unroll
    for (int n = 0; n < 3; ++n) {
      bf16x8 b = *(const bf16x8*)&Bs[n * 16 + fr][kb];
      acc[n] = __builtin_amdgcn_mfma_f32_16x16x32_bf16(a, b, acc[n], 0, 0, 0);
    }
  }

  const int r0 = row0 + wid * 16 + fg * 4;
#pragma unroll
  for (int n = 0; n < 3; ++n) {
    const int cn = n * 16 + fr;
    if (cn < 40) {
      const float bv = bc[cn];
#pragma unroll
      for (int i = 0; i < 4; ++i) {
        const int rr = r0 + i;
        if (rr < nrows) out[(size_t)rr * 40 + cn] = acc[n][i] + bv;
      }
    }
  }
}

extern "C" void kernel_launch(void* const* d_in, const int* in_sizes, int n_in,
                              void* d_out, int out_size, void* d_ws, size_t ws_size,
                              hipStream_t stream) {
  const float* x     = (const float*)d_in[0];
  const int*   ei    = (const int*)d_in[1];
  const float* W_in  = (const float*)d_in[2];
  const float* b_in  = (const float*)d_in[3];
  const float* W_gcn = (const float*)d_in[4];
  const float* b_gcn = (const float*)d_in[5];
  const float* W_cls = (const float*)d_in[6];
  const float* b_cls = (const float*)d_in[7];
  float* out = (float*)d_out;

  const int N = in_sizes[0] / 128;
  const int E = in_sizes[1] / 2;
  const int* row = ei;
  const int* col = ei + E;

  const int sortb = (E + CH_MAX - 1) / CH_MAX;       // 128 for E=600000
  const int chunk = (E + sortb - 1) / sortb;          // <= CH_MAX
  const int nscan = NBUCK * sortb;                    // 65536
  const int nblk  = (nscan + 1023) / 1024;            // 64
  const int nbuck = (N + 127) >> 7;                   // 391

  // d_ws: h bf16 (N*128), xws bf16 (N*128), Wt buffers
  ushort* h   = (ushort*)d_ws;
  ushort* xws = h + (size_t)N * 128;
  ushort* Wti = xws + (size_t)N * 128;
  ushort* Wtg = Wti + 128 * 128;
  ushort* Wtc = Wtg + 128 * 128;                      // 48 x 128 zero-padded
  // scratch parked in d_out (fully overwritten by k_out_mfma at the end):
  uint*  ebuf   = (uint*)d_out;                       // E uints      (2.4 MB)
  int*   srcrow = (int*)d_out + E;                    // E ints       (2.4 MB)
  int*   H      = (int*)d_out + 2 * (size_t)E;        // nscan ints   (256 KB)
  int*   aux    = H + nscan;                          // nblk ints
  int*   P      = aux + nblk;                         // N ints       (200 KB)
  float* dinv   = (float*)(P + N);                    // N floats     (200 KB)

  k_prep<<<152, 256, 0, stream>>>(W_in, W_gcn, W_cls, Wti, Wtg, Wtc);

  // two-level bucket sort of edges by col
  k_chist<<<sortb, 256, 0, stream>>>(col, H, E, chunk);
  k_scan1<<<nblk, 256, 0, stream>>>(H, aux, nscan);
  k_scan2<<<1, 64, 0, stream>>>(aux, nblk);
  k_scan3<<<nblk, 256, 0, stream>>>(H, aux, nscan);
  k_reorder<<<sortb, 256, 0, stream>>>(row, col, H, ebuf, E, chunk);
  k_sort2<<<nbuck, 256, 0, stream>>>(ebuf, H, srcrow, P, dinv, sortb, N);

  // h = relu(x @ W_in + b_in)
  k_gemm_mfma<true, true, false, false>
      <<<(N + 63) / 64, 256, 0, stream>>>(x, Wti, b_in, nullptr, h, N);

  // xws = dinv[r] * (h @ W_gcn)
  k_gemm_mfma<false, false, true, true>
      <<<(N + 63) / 64, 256, 0, stream>>>(h, Wtg, nullptr, dinv, xws, N);

  // t = relu(dinv[c]*(sum_{e->c} xws[r] + xws[c]) + b_gcn)   (t -> h buffer)
  k_agg<<<(N + 3) / 4, 256, 0, stream>>>(P, srcrow, xws, dinv, b_gcn, h, N);

  // out = t @ W_cls + b_cls
  k_out_mfma<<<(N + 63) / 64, 256, 0, stream>>>(h, Wtc, b_cls, out, N);
}

// Round 7
// 116.015 us; speedup vs baseline: 5.1918x; 1.0188x over previous
//
#include <hip/hip_runtime.h>

// ---------------------------------------------------------------------------
// PYG_GCN: y = relu(x@W_in+b_in) -> GCNConv(W_gcn,b_gcn) -> relu -> @W_cls+b_cls
// N=50000, E=600000, D=128, C=40.
// R7: 6 launches. Fused GEMM1+GEMM2 (h stays in LDS), fused agg+cls-out
// (t stays in LDS), slimmed bucket sort (atomic cursors, 512-scan only).
// All scratch in d_ws (aggout reads CSR while writing d_out).
// ---------------------------------------------------------------------------

typedef __bf16 bf16x8 __attribute__((ext_vector_type(8)));
typedef float f32x4 __attribute__((ext_vector_type(4)));

#define NBUCK 512      // bucket = col>>7; used 0..390 for N=50000
#define CH_MAX 4704    // max edges per sort-chunk block
#define PREP_BLKS 152  // 38912 weight elements / 256

__device__ __forceinline__ ushort f2b(float f) {  // fp32 -> bf16 RNE
  uint u = __float_as_uint(f);
  return (ushort)((u + 0x7FFFu + ((u >> 16) & 1u)) >> 16);
}
__device__ __forceinline__ float b2f_lo(uint u) { return __uint_as_float(u << 16); }
__device__ __forceinline__ float b2f_hi(uint u) { return __uint_as_float(u & 0xFFFF0000u); }

// ---------------- prep (blocks 0..151) + coarse chist (rest) ---------------
// H2 layout bucket-major: H2[b*sortb + chunk_blk] (pure stores, no zeroing).
__global__ __launch_bounds__(256) void k_prep_chist(const float* __restrict__ Wi,
                                                    const float* __restrict__ Wg,
                                                    const float* __restrict__ Wc,
                                                    ushort* __restrict__ Ti,
                                                    ushort* __restrict__ Tg,
                                                    ushort* __restrict__ Tc,
                                                    const int* __restrict__ col,
                                                    int* __restrict__ H2,
                                                    int E, int chunk, int sortb) {
  __shared__ int hist[NBUCK];
  const int tid = threadIdx.x;
  if (blockIdx.x < PREP_BLKS) {
    int idx = blockIdx.x * 256 + tid;
    if (idx < 16384) {
      int c = idx >> 7, k = idx & 127;
      Ti[c * 128 + k] = f2b(Wi[k * 128 + c]);
    } else if (idx < 32768) {
      int j = idx - 16384;
      int c = j >> 7, k = j & 127;
      Tg[c * 128 + k] = f2b(Wg[k * 128 + c]);
    } else if (idx < 38912) {
      int j = idx - 32768;
      int c = j >> 7, k = j & 127;
      Tc[c * 128 + k] = (c < 40) ? f2b(Wc[k * 40 + c]) : (ushort)0;
    }
    return;
  }
  const int blk = blockIdx.x - PREP_BLKS;
  for (int b = tid; b < NBUCK; b += 256) hist[b] = 0;
  __syncthreads();
  const int e0 = blk * chunk;
  const int cnt = min(chunk, E - e0);
  for (int i = tid; i < cnt; i += 256)
    atomicAdd(&hist[((unsigned)col[e0 + i]) >> 7], 1);
  __syncthreads();
  for (int b = tid; b < NBUCK; b += 256)
    H2[b * sortb + blk] = hist[b];
}

// ---------------- single-block: reduce H2 -> scan 512 -> Hs; zero cursor ---
__global__ __launch_bounds__(256) void k_scanH(const int* __restrict__ H2,
                                               int* __restrict__ Hs,
                                               int* __restrict__ cursor,
                                               int sortb) {
  __shared__ int sd[256];
  const int t = threadIdx.x;
  int s0 = 0, s1 = 0;
  const int* p0 = &H2[(2 * t) * sortb];
  const int* p1 = &H2[(2 * t + 1) * sortb];
  for (int j = 0; j < sortb; ++j) { s0 += p0[j]; s1 += p1[j]; }
  const int ps = s0 + s1;
  sd[t] = ps;
  __syncthreads();
  for (int off = 1; off < 256; off <<= 1) {
    int u = (t >= off) ? sd[t - off] : 0;
    __syncthreads();
    sd[t] += u;
    __syncthreads();
  }
  const int ex = sd[t] - ps;
  Hs[2 * t] = ex;
  Hs[2 * t + 1] = ex + s0;
  if (t == 255) Hs[NBUCK] = ex + ps;  // == E
  cursor[2 * t] = 0;
  cursor[2 * t + 1] = 0;
}

// ---------------- reorder: LDS-pack chunk by bucket, atomic-cursor bases ---
// ebuf record: (c_local<<16) | row  (row < 65536 since N=50000).
__global__ __launch_bounds__(256) void k_reorder(const int* __restrict__ row,
                                                 const int* __restrict__ col,
                                                 const int* __restrict__ Hs,
                                                 int* __restrict__ cursor,
                                                 uint* __restrict__ ebuf,
                                                 int E, int chunk) {
  __shared__ int hist[NBUCK];
  __shared__ int lstart[NBUCK];
  __shared__ int cnt2[NBUCK];
  __shared__ int obase[NBUCK];
  __shared__ uint data[CH_MAX];
  __shared__ int gpos[CH_MAX];
  __shared__ int sd[256];
  const int tid = threadIdx.x;
  for (int b = tid; b < NBUCK; b += 256) { hist[b] = 0; cnt2[b] = 0; }
  __syncthreads();
  const int e0 = blockIdx.x * chunk;
  const int cnt = min(chunk, E - e0);
  for (int i = tid; i < cnt; i += 256)
    atomicAdd(&hist[((unsigned)col[e0 + i]) >> 7], 1);
  __syncthreads();
  const int h0 = hist[2 * tid], h1 = hist[2 * tid + 1];
  const int ps = h0 + h1;
  sd[tid] = ps;
  __syncthreads();
  for (int off = 1; off < 256; off <<= 1) {
    int u = (tid >= off) ? sd[tid - off] : 0;
    __syncthreads();
    sd[tid] += u;
    __syncthreads();
  }
  const int ex = sd[tid] - ps;
  lstart[2 * tid] = ex;
  lstart[2 * tid + 1] = ex + h0;
  // claim this chunk's output range in each bucket (order in-bucket arbitrary)
  obase[2 * tid]     = Hs[2 * tid]     + (h0 ? atomicAdd(&cursor[2 * tid], h0) : 0);
  obase[2 * tid + 1] = Hs[2 * tid + 1] + (h1 ? atomicAdd(&cursor[2 * tid + 1], h1) : 0);
  __syncthreads();
  for (int i = tid; i < cnt; i += 256) {
    const int c = col[e0 + i], r = row[e0 + i];
    const int b = ((unsigned)c) >> 7;
    const int rk = atomicAdd(&cnt2[b], 1);
    const int slot = lstart[b] + rk;
    data[slot] = ((uint)(c & 127) << 16) | (uint)r;
    gpos[slot] = obase[b] + rk;
  }
  __syncthreads();
  for (int i = tid; i < cnt; i += 256)
    ebuf[gpos[i]] = data[i];
}

// ---------------- per-bucket fine sort -> srcrow CSR + P + dinv ------------
// P[node] = END offset of node's segment (seg = [P[c-1], P[c]), P[-1] := 0).
__global__ __launch_bounds__(256) void k_sort2(const uint* __restrict__ ebuf,
                                               const int* __restrict__ Hs,
                                               int* __restrict__ srcrow,
                                               int* __restrict__ P,
                                               float* __restrict__ dinv,
                                               int n) {
  __shared__ int cnt[128];
  __shared__ int lstart[128];
  __shared__ int cnt2[128];
  __shared__ int sd[256];
  const int tid = threadIdx.x;
  if (tid < 128) { cnt[tid] = 0; cnt2[tid] = 0; }
  __syncthreads();
  const int b = blockIdx.x;
  const int start = Hs[b];
  const int end = Hs[b + 1];
  for (int i = start + tid; i < end; i += 256)
    atomicAdd(&cnt[ebuf[i] >> 16], 1);
  __syncthreads();
  const int cv = (tid < 128) ? cnt[tid] : 0;
  sd[tid] = cv;
  __syncthreads();
  for (int off = 1; off < 256; off <<= 1) {
    int u = (tid >= off) ? sd[tid - off] : 0;
    __syncthreads();
    sd[tid] += u;
    __syncthreads();
  }
  if (tid < 128) {
    const int ex = sd[tid] - cv;
    lstart[tid] = ex;
    const int node = b * 128 + tid;
    if (node < n) {
      P[node] = start + ex + cv;
      dinv[node] = rsqrtf((float)cv + 1.0f);
    }
  }
  __syncthreads();
  for (int i = start + tid; i < end; i += 256) {
    const uint v = ebuf[i];
    const int c = v >> 16;
    const int rk = atomicAdd(&cnt2[c], 1);
    srcrow[start + lstart[c] + rk] = (int)(v & 0xFFFFu);
  }
}

// ---------------------------------------------------------------------------
// Fused GEMM1+GEMM2: xws = dinv[r] * (relu(x@W_in + b_in) @ W_gcn).
// h tile never leaves LDS. Wtg re-staged per block (32KB, L2-resident).
// ---------------------------------------------------------------------------
__global__ __launch_bounds__(256) void k_gemm12(const float* __restrict__ x,
                                                const ushort* __restrict__ Wti,
                                                const ushort* __restrict__ Wtg,
                                                const float* __restrict__ b_in,
                                                const float* __restrict__ dinv,
                                                ushort* __restrict__ xws, int nrows) {
  __shared__ ushort As[64][136];
  __shared__ ushort Bs[128][136];
  const int tid = threadIdx.x;
  const int row0 = blockIdx.x * 64;

#pragma unroll
  for (int q = 0; q < 8; ++q) {
    int f = tid + 256 * q;
    int r = f >> 4, cw = f & 15;
    *(uint4*)&Bs[r][cw * 8] = *(const uint4*)&Wti[r * 128 + cw * 8];
  }
#pragma unroll
  for (int q = 0; q < 8; ++q) {
    int f = tid + 256 * q;
    int r = f >> 5, kc = f & 31;
    float4 v = make_float4(0.f, 0.f, 0.f, 0.f);
    if (row0 + r < nrows) v = *(const float4*)&x[(size_t)(row0 + r) * 128 + kc * 4];
    ushort4 o;
    o.x = f2b(v.x); o.y = f2b(v.y); o.z = f2b(v.z); o.w = f2b(v.w);
    *(ushort4*)&As[r][kc * 4] = o;
  }
  __syncthreads();

  const int wid = tid >> 6, lane = tid & 63;
  const int fr = lane & 15;
  const int fg = lane >> 4;

  f32x4 acc[8];
#pragma unroll
  for (int n = 0; n < 8; ++n) acc[n] = (f32x4){0.f, 0.f, 0.f, 0.f};
#pragma unroll
  for (int ks = 0; ks < 4; ++ks) {
    const int kb = ks * 32 + fg * 8;
    bf16x8 a = *(const bf16x8*)&As[wid * 16 + fr][kb];
#pragma unroll
    for (int n = 0; n < 8; ++n) {
      bf16x8 b = *(const bf16x8*)&Bs[n * 16 + fr][kb];
      acc[n] = __builtin_amdgcn_mfma_f32_16x16x32_bf16(a, b, acc[n], 0, 0, 0);
    }
  }
  __syncthreads();  // all As/Bs reads of stage-1 done

  // h = relu(acc + b_in) -> bf16 back into As (D-frag layout); restage Wtg
#pragma unroll
  for (int n = 0; n < 8; ++n) {
    const int cn = n * 16 + fr;
    const float bv = b_in[cn];
#pragma unroll
    for (int i = 0; i < 4; ++i)
      As[wid * 16 + fg * 4 + i][cn] = f2b(fmaxf(acc[n][i] + bv, 0.f));
  }
#pragma unroll
  for (int q = 0; q < 8; ++q) {
    int f = tid + 256 * q;
    int r = f >> 4, cw = f & 15;
    *(uint4*)&Bs[r][cw * 8] = *(const uint4*)&Wtg[r * 128 + cw * 8];
  }
  __syncthreads();

  f32x4 acc2[8];
#pragma unroll
  for (int n = 0; n < 8; ++n) acc2[n] = (f32x4){0.f, 0.f, 0.f, 0.f};
#pragma unroll
  for (int ks = 0; ks < 4; ++ks) {
    const int kb = ks * 32 + fg * 8;
    bf16x8 a = *(const bf16x8*)&As[wid * 16 + fr][kb];
#pragma unroll
    for (int n = 0; n < 8; ++n) {
      bf16x8 b = *(const bf16x8*)&Bs[n * 16 + fr][kb];
      acc2[n] = __builtin_amdgcn_mfma_f32_16x16x32_bf16(a, b, acc2[n], 0, 0, 0);
    }
  }

  const int r0 = row0 + wid * 16 + fg * 4;
  float dv[4];
#pragma unroll
  for (int i = 0; i < 4; ++i) dv[i] = (r0 + i < nrows) ? dinv[r0 + i] : 0.f;
#pragma unroll
  for (int n = 0; n < 8; ++n) {
    const int cn = n * 16 + fr;
#pragma unroll
    for (int i = 0; i < 4; ++i) {
      const int rr = r0 + i;
      if (rr < nrows) xws[(size_t)rr * 128 + cn] = f2b(acc2[n][i] * dv[i]);
    }
  }
}

// ---------------------------------------------------------------------------
// Fused aggregate + classifier. 1024 threads: 16 waves x 4 nodes (gather TLP
// preserved: 12.5k waves), t rows in LDS, then 12 waves do 64x128x48 MFMA.
// ---------------------------------------------------------------------------
__global__ __launch_bounds__(1024) void k_aggout(const int* __restrict__ P,
                                                 const int* __restrict__ srcrow,
                                                 const ushort* __restrict__ xws,
                                                 const float* __restrict__ dinv,
                                                 const float* __restrict__ b_gcn,
                                                 const ushort* __restrict__ Wtc,
                                                 const float* __restrict__ bc,
                                                 float* __restrict__ out, int n) {
  __shared__ ushort ts[64][136];
  __shared__ ushort Bs[48][136];
  const int tid = threadIdx.x;
  if (tid < 768) {
    int r = tid >> 4, cw = tid & 15;
    *(uint4*)&Bs[r][cw * 8] = *(const uint4*)&Wtc[r * 128 + cw * 8];
  }
  const int wid = tid >> 6, lane = tid & 63;
  const int row0 = blockIdx.x * 64;
  const size_t off = (size_t)lane * 2;
  const float2 bg = *(const float2*)&b_gcn[lane * 2];

#pragma unroll
  for (int i = 0; i < 4; ++i) {
    const int rl = wid * 4 + i;
    const int c = row0 + rl;
    ushort2 o = make_ushort2(0, 0);
    if (c < n) {
      const int begin = (c == 0) ? 0 : P[c - 1];
      const int end = P[c];
      uint s = *(const uint*)&xws[(size_t)c * 128 + off];  // self term
      float ax = b2f_lo(s), ay = b2f_hi(s);
      int e = begin;
      for (; e + 4 <= end; e += 4) {
        int r0 = srcrow[e], r1 = srcrow[e + 1], r2 = srcrow[e + 2], r3 = srcrow[e + 3];
        uint v0 = *(const uint*)&xws[(size_t)r0 * 128 + off];
        uint v1 = *(const uint*)&xws[(size_t)r1 * 128 + off];
        uint v2 = *(const uint*)&xws[(size_t)r2 * 128 + off];
        uint v3 = *(const uint*)&xws[(size_t)r3 * 128 + off];
        ax += (b2f_lo(v0) + b2f_lo(v1)) + (b2f_lo(v2) + b2f_lo(v3));
        ay += (b2f_hi(v0) + b2f_hi(v1)) + (b2f_hi(v2) + b2f_hi(v3));
      }
      for (; e < end; ++e) {
        uint v = *(const uint*)&xws[(size_t)srcrow[e] * 128 + off];
        ax += b2f_lo(v);
        ay += b2f_hi(v);
      }
      const float dc = dinv[c];
      o.x = f2b(fmaxf(fmaf(dc, ax, bg.x), 0.f));
      o.y = f2b(fmaxf(fmaf(dc, ay, bg.y), 0.f));
    }
    *(ushort2*)&ts[rl][off] = o;
  }
  __syncthreads();

  if (wid < 12) {
    const int rb = wid & 3, nb = wid >> 2;
    const int fr = lane & 15, fg = lane >> 4;
    f32x4 acc = (f32x4){0.f, 0.f, 0.f, 0.f};
#pragma unroll
    for (int ks = 0; ks < 4; ++ks) {
      const int kb = ks * 32 + fg * 8;
      bf16x8 a = *(const bf16x8*)&ts[rb * 16 + fr][kb];
      bf16x8 b = *(const bf16x8*)&Bs[nb * 16 + fr][kb];
      acc = __builtin_amdgcn_mfma_f32_16x16x32_bf16(a, b, acc, 0, 0, 0);
    }
    const int cn = nb * 16 + fr;
    if (cn < 40) {
      const float bv = bc[cn];
      const int r0 = row0 + rb * 16 + fg * 4;
#pragma unroll
      for (int i = 0; i < 4; ++i) {
        const int rr = r0 + i;
        if (rr < n) out[(size_t)rr * 40 + cn] = acc[i] + bv;
      }
    }
  }
}

extern "C" void kernel_launch(void* const* d_in, const int* in_sizes, int n_in,
                              void* d_out, int out_size, void* d_ws, size_t ws_size,
                              hipStream_t stream) {
  const float* x     = (const float*)d_in[0];
  const int*   ei    = (const int*)d_in[1];
  const float* W_in  = (const float*)d_in[2];
  const float* b_in  = (const float*)d_in[3];
  const float* W_gcn = (const float*)d_in[4];
  const float* b_gcn = (const float*)d_in[5];
  const float* W_cls = (const float*)d_in[6];
  const float* b_cls = (const float*)d_in[7];
  float* out = (float*)d_out;

  const int N = in_sizes[0] / 128;
  const int E = in_sizes[1] / 2;
  const int* row = ei;
  const int* col = ei + E;

  const int sortb = (E + CH_MAX - 1) / CH_MAX;   // 128 for E=600000
  const int chunk = (E + sortb - 1) / sortb;      // <= CH_MAX
  const int nbuck = (N + 127) >> 7;               // 391

  // d_ws layout (~18.3 MB): xws, weights, sort scratch, CSR
  ushort* xws    = (ushort*)d_ws;                 // N*128 bf16
  ushort* Wti    = xws + (size_t)N * 128;         // 128x128
  ushort* Wtg    = Wti + 128 * 128;               // 128x128
  ushort* Wtc    = Wtg + 128 * 128;               // 48x128 zero-padded
  uint*   ebuf   = (uint*)(Wtc + 48 * 128);       // E
  int*    srcrow = (int*)(ebuf + E);              // E
  int*    H2     = srcrow + E;                    // NBUCK*sortb
  int*    Hs     = H2 + NBUCK * sortb;            // NBUCK+1
  int*    cursor = Hs + NBUCK + 1;                // NBUCK
  int*    P      = cursor + NBUCK;                // N
  float*  dinv   = (float*)(P + N);               // N

  // weight prep + per-chunk coarse histogram (fused)
  k_prep_chist<<<PREP_BLKS + sortb, 256, 0, stream>>>(W_in, W_gcn, W_cls,
                                                      Wti, Wtg, Wtc,
                                                      col, H2, E, chunk, sortb);
  // reduce+scan 512 buckets, zero cursors
  k_scanH<<<1, 256, 0, stream>>>(H2, Hs, cursor, sortb);
  // pack edges by bucket (in-bucket order arbitrary)
  k_reorder<<<sortb, 256, 0, stream>>>(row, col, Hs, cursor, ebuf, E, chunk);
  // per-bucket fine sort -> srcrow CSR + P + dinv
  k_sort2<<<nbuck, 256, 0, stream>>>(ebuf, Hs, srcrow, P, dinv, N);

  // xws = dinv[r] * (relu(x@W_in + b_in) @ W_gcn)
  k_gemm12<<<(N + 63) / 64, 256, 0, stream>>>(x, Wti, Wtg, b_in, dinv, xws, N);

  // out = relu(dinv[c]*(sum xws[r] + xws[c]) + b_gcn) @ W_cls + b_cls
  k_aggout<<<(N + 63) / 64, 1024, 0, stream>>>(P, srcrow, xws, dinv, b_gcn,
                                               Wtc, b_cls, out, N);
}

// Round 8
// 115.740 us; speedup vs baseline: 5.2041x; 1.0024x over previous
//
#include <hip/hip_runtime.h>

// ---------------------------------------------------------------------------
// PYG_GCN: y = relu(x@W_in+b_in) -> GCNConv(W_gcn,b_gcn) -> relu -> @W_cls+b_cls
// N=50000, E=600000, D=128, C=40.
// R8: same as R7 except k_aggout rebuilt: 512 threads / 32 nodes per block,
// LDS work-queue node stealing (degree-imbalance tail), 6/8 waves in MFMA.
// ---------------------------------------------------------------------------

typedef __bf16 bf16x8 __attribute__((ext_vector_type(8)));
typedef float f32x4 __attribute__((ext_vector_type(4)));

#define NBUCK 512      // bucket = col>>7; used 0..390 for N=50000
#define CH_MAX 4704    // max edges per sort-chunk block
#define PREP_BLKS 152  // 38912 weight elements / 256

__device__ __forceinline__ ushort f2b(float f) {  // fp32 -> bf16 RNE
  uint u = __float_as_uint(f);
  return (ushort)((u + 0x7FFFu + ((u >> 16) & 1u)) >> 16);
}
__device__ __forceinline__ float b2f_lo(uint u) { return __uint_as_float(u << 16); }
__device__ __forceinline__ float b2f_hi(uint u) { return __uint_as_float(u & 0xFFFF0000u); }

// ---------------- prep (blocks 0..151) + coarse chist (rest) ---------------
// H2 layout bucket-major: H2[b*sortb + chunk_blk] (pure stores, no zeroing).
__global__ __launch_bounds__(256) void k_prep_chist(const float* __restrict__ Wi,
                                                    const float* __restrict__ Wg,
                                                    const float* __restrict__ Wc,
                                                    ushort* __restrict__ Ti,
                                                    ushort* __restrict__ Tg,
                                                    ushort* __restrict__ Tc,
                                                    const int* __restrict__ col,
                                                    int* __restrict__ H2,
                                                    int E, int chunk, int sortb) {
  __shared__ int hist[NBUCK];
  const int tid = threadIdx.x;
  if (blockIdx.x < PREP_BLKS) {
    int idx = blockIdx.x * 256 + tid;
    if (idx < 16384) {
      int c = idx >> 7, k = idx & 127;
      Ti[c * 128 + k] = f2b(Wi[k * 128 + c]);
    } else if (idx < 32768) {
      int j = idx - 16384;
      int c = j >> 7, k = j & 127;
      Tg[c * 128 + k] = f2b(Wg[k * 128 + c]);
    } else if (idx < 38912) {
      int j = idx - 32768;
      int c = j >> 7, k = j & 127;
      Tc[c * 128 + k] = (c < 40) ? f2b(Wc[k * 40 + c]) : (ushort)0;
    }
    return;
  }
  const int blk = blockIdx.x - PREP_BLKS;
  for (int b = tid; b < NBUCK; b += 256) hist[b] = 0;
  __syncthreads();
  const int e0 = blk * chunk;
  const int cnt = min(chunk, E - e0);
  for (int i = tid; i < cnt; i += 256)
    atomicAdd(&hist[((unsigned)col[e0 + i]) >> 7], 1);
  __syncthreads();
  for (int b = tid; b < NBUCK; b += 256)
    H2[b * sortb + blk] = hist[b];
}

// ---------------- single-block: reduce H2 -> scan 512 -> Hs; zero cursor ---
__global__ __launch_bounds__(256) void k_scanH(const int* __restrict__ H2,
                                               int* __restrict__ Hs,
                                               int* __restrict__ cursor,
                                               int sortb) {
  __shared__ int sd[256];
  const int t = threadIdx.x;
  int s0 = 0, s1 = 0;
  const int* p0 = &H2[(2 * t) * sortb];
  const int* p1 = &H2[(2 * t + 1) * sortb];
  for (int j = 0; j < sortb; ++j) { s0 += p0[j]; s1 += p1[j]; }
  const int ps = s0 + s1;
  sd[t] = ps;
  __syncthreads();
  for (int off = 1; off < 256; off <<= 1) {
    int u = (t >= off) ? sd[t - off] : 0;
    __syncthreads();
    sd[t] += u;
    __syncthreads();
  }
  const int ex = sd[t] - ps;
  Hs[2 * t] = ex;
  Hs[2 * t + 1] = ex + s0;
  if (t == 255) Hs[NBUCK] = ex + ps;  // == E
  cursor[2 * t] = 0;
  cursor[2 * t + 1] = 0;
}

// ---------------- reorder: LDS-pack chunk by bucket, atomic-cursor bases ---
// ebuf record: (c_local<<16) | row  (row < 65536 since N=50000).
__global__ __launch_bounds__(256) void k_reorder(const int* __restrict__ row,
                                                 const int* __restrict__ col,
                                                 const int* __restrict__ Hs,
                                                 int* __restrict__ cursor,
                                                 uint* __restrict__ ebuf,
                                                 int E, int chunk) {
  __shared__ int hist[NBUCK];
  __shared__ int lstart[NBUCK];
  __shared__ int cnt2[NBUCK];
  __shared__ int obase[NBUCK];
  __shared__ uint data[CH_MAX];
  __shared__ int gpos[CH_MAX];
  __shared__ int sd[256];
  const int tid = threadIdx.x;
  for (int b = tid; b < NBUCK; b += 256) { hist[b] = 0; cnt2[b] = 0; }
  __syncthreads();
  const int e0 = blockIdx.x * chunk;
  const int cnt = min(chunk, E - e0);
  for (int i = tid; i < cnt; i += 256)
    atomicAdd(&hist[((unsigned)col[e0 + i]) >> 7], 1);
  __syncthreads();
  const int h0 = hist[2 * tid], h1 = hist[2 * tid + 1];
  const int ps = h0 + h1;
  sd[tid] = ps;
  __syncthreads();
  for (int off = 1; off < 256; off <<= 1) {
    int u = (tid >= off) ? sd[tid - off] : 0;
    __syncthreads();
    sd[tid] += u;
    __syncthreads();
  }
  const int ex = sd[tid] - ps;
  lstart[2 * tid] = ex;
  lstart[2 * tid + 1] = ex + h0;
  // claim this chunk's output range in each bucket (order in-bucket arbitrary)
  obase[2 * tid]     = Hs[2 * tid]     + (h0 ? atomicAdd(&cursor[2 * tid], h0) : 0);
  obase[2 * tid + 1] = Hs[2 * tid + 1] + (h1 ? atomicAdd(&cursor[2 * tid + 1], h1) : 0);
  __syncthreads();
  for (int i = tid; i < cnt; i += 256) {
    const int c = col[e0 + i], r = row[e0 + i];
    const int b = ((unsigned)c) >> 7;
    const int rk = atomicAdd(&cnt2[b], 1);
    const int slot = lstart[b] + rk;
    data[slot] = ((uint)(c & 127) << 16) | (uint)r;
    gpos[slot] = obase[b] + rk;
  }
  __syncthreads();
  for (int i = tid; i < cnt; i += 256)
    ebuf[gpos[i]] = data[i];
}

// ---------------- per-bucket fine sort -> srcrow CSR + P + dinv ------------
// P[node] = END offset of node's segment (seg = [P[c-1], P[c]), P[-1] := 0).
__global__ __launch_bounds__(256) void k_sort2(const uint* __restrict__ ebuf,
                                               const int* __restrict__ Hs,
                                               int* __restrict__ srcrow,
                                               int* __restrict__ P,
                                               float* __restrict__ dinv,
                                               int n) {
  __shared__ int cnt[128];
  __shared__ int lstart[128];
  __shared__ int cnt2[128];
  __shared__ int sd[256];
  const int tid = threadIdx.x;
  if (tid < 128) { cnt[tid] = 0; cnt2[tid] = 0; }
  __syncthreads();
  const int b = blockIdx.x;
  const int start = Hs[b];
  const int end = Hs[b + 1];
  for (int i = start + tid; i < end; i += 256)
    atomicAdd(&cnt[ebuf[i] >> 16], 1);
  __syncthreads();
  const int cv = (tid < 128) ? cnt[tid] : 0;
  sd[tid] = cv;
  __syncthreads();
  for (int off = 1; off < 256; off <<= 1) {
    int u = (tid >= off) ? sd[tid - off] : 0;
    __syncthreads();
    sd[tid] += u;
    __syncthreads();
  }
  if (tid < 128) {
    const int ex = sd[tid] - cv;
    lstart[tid] = ex;
    const int node = b * 128 + tid;
    if (node < n) {
      P[node] = start + ex + cv;
      dinv[node] = rsqrtf((float)cv + 1.0f);
    }
  }
  __syncthreads();
  for (int i = start + tid; i < end; i += 256) {
    const uint v = ebuf[i];
    const int c = v >> 16;
    const int rk = atomicAdd(&cnt2[c], 1);
    srcrow[start + lstart[c] + rk] = (int)(v & 0xFFFFu);
  }
}

// ---------------------------------------------------------------------------
// Fused GEMM1+GEMM2: xws = dinv[r] * (relu(x@W_in + b_in) @ W_gcn).
// h tile never leaves LDS. Wtg re-staged per block (32KB, L2-resident).
// ---------------------------------------------------------------------------
__global__ __launch_bounds__(256) void k_gemm12(const float* __restrict__ x,
                                                const ushort* __restrict__ Wti,
                                                const ushort* __restrict__ Wtg,
                                                const float* __restrict__ b_in,
                                                const float* __restrict__ dinv,
                                                ushort* __restrict__ xws, int nrows) {
  __shared__ ushort As[64][136];
  __shared__ ushort Bs[128][136];
  const int tid = threadIdx.x;
  const int row0 = blockIdx.x * 64;

#pragma unroll
  for (int q = 0; q < 8; ++q) {
    int f = tid + 256 * q;
    int r = f >> 4, cw = f & 15;
    *(uint4*)&Bs[r][cw * 8] = *(const uint4*)&Wti[r * 128 + cw * 8];
  }
#pragma unroll
  for (int q = 0; q < 8; ++q) {
    int f = tid + 256 * q;
    int r = f >> 5, kc = f & 31;
    float4 v = make_float4(0.f, 0.f, 0.f, 0.f);
    if (row0 + r < nrows) v = *(const float4*)&x[(size_t)(row0 + r) * 128 + kc * 4];
    ushort4 o;
    o.x = f2b(v.x); o.y = f2b(v.y); o.z = f2b(v.z); o.w = f2b(v.w);
    *(ushort4*)&As[r][kc * 4] = o;
  }
  __syncthreads();

  const int wid = tid >> 6, lane = tid & 63;
  const int fr = lane & 15;
  const int fg = lane >> 4;

  f32x4 acc[8];
#pragma unroll
  for (int n = 0; n < 8; ++n) acc[n] = (f32x4){0.f, 0.f, 0.f, 0.f};
#pragma unroll
  for (int ks = 0; ks < 4; ++ks) {
    const int kb = ks * 32 + fg * 8;
    bf16x8 a = *(const bf16x8*)&As[wid * 16 + fr][kb];
#pragma unroll
    for (int n = 0; n < 8; ++n) {
      bf16x8 b = *(const bf16x8*)&Bs[n * 16 + fr][kb];
      acc[n] = __builtin_amdgcn_mfma_f32_16x16x32_bf16(a, b, acc[n], 0, 0, 0);
    }
  }
  __syncthreads();  // all As/Bs reads of stage-1 done

  // h = relu(acc + b_in) -> bf16 back into As (D-frag layout); restage Wtg
#pragma unroll
  for (int n = 0; n < 8; ++n) {
    const int cn = n * 16 + fr;
    const float bv = b_in[cn];
#pragma unroll
    for (int i = 0; i < 4; ++i)
      As[wid * 16 + fg * 4 + i][cn] = f2b(fmaxf(acc[n][i] + bv, 0.f));
  }
#pragma unroll
  for (int q = 0; q < 8; ++q) {
    int f = tid + 256 * q;
    int r = f >> 4, cw = f & 15;
    *(uint4*)&Bs[r][cw * 8] = *(const uint4*)&Wtg[r * 128 + cw * 8];
  }
  __syncthreads();

  f32x4 acc2[8];
#pragma unroll
  for (int n = 0; n < 8; ++n) acc2[n] = (f32x4){0.f, 0.f, 0.f, 0.f};
#pragma unroll
  for (int ks = 0; ks < 4; ++ks) {
    const int kb = ks * 32 + fg * 8;
    bf16x8 a = *(const bf16x8*)&As[wid * 16 + fr][kb];
#pragma unroll
    for (int n = 0; n < 8; ++n) {
      bf16x8 b = *(const bf16x8*)&Bs[n * 16 + fr][kb];
      acc2[n] = __builtin_amdgcn_mfma_f32_16x16x32_bf16(a, b, acc2[n], 0, 0, 0);
    }
  }

  const int r0 = row0 + wid * 16 + fg * 4;
  float dv[4];
#pragma unroll
  for (int i = 0; i < 4; ++i) dv[i] = (r0 + i < nrows) ? dinv[r0 + i] : 0.f;
#pragma unroll
  for (int n = 0; n < 8; ++n) {
    const int cn = n * 16 + fr;
#pragma unroll
    for (int i = 0; i < 4; ++i) {
      const int rr = r0 + i;
      if (rr < nrows) xws[(size_t)rr * 128 + cn] = f2b(acc2[n][i] * dv[i]);
    }
  }
}

// ---------------------------------------------------------------------------
// Fused aggregate + classifier, 512 threads / 32 nodes per block.
// 8 waves pull nodes from an LDS work-queue (degree-imbalance smoothing);
// gather wave-per-node, lane owns 2 cols. Then 6 waves do 32x128x48 MFMA.
// ---------------------------------------------------------------------------
__global__ __launch_bounds__(512) void k_aggout(const int* __restrict__ P,
                                                const int* __restrict__ srcrow,
                                                const ushort* __restrict__ xws,
                                                const float* __restrict__ dinv,
                                                const float* __restrict__ b_gcn,
                                                const ushort* __restrict__ Wtc,
                                                const float* __restrict__ bc,
                                                float* __restrict__ out, int n) {
  __shared__ ushort ts[32][136];
  __shared__ ushort Bs[48][136];
  __shared__ int nextn;
  const int tid = threadIdx.x;
  // stage W_cls tile: 48*136 -> 768 uint4 chunks
#pragma unroll
  for (int q = 0; q < 2; ++q) {
    int f = tid + 512 * q;
    if (f < 768) {
      int r = f >> 4, cw = f & 15;
      *(uint4*)&Bs[r][cw * 8] = *(const uint4*)&Wtc[r * 128 + cw * 8];
    }
  }
  if (tid == 0) nextn = 0;
  __syncthreads();

  const int wid = tid >> 6, lane = tid & 63;
  const int row0 = blockIdx.x * 32;
  const size_t off = (size_t)lane * 2;
  const float2 bg = *(const float2*)&b_gcn[lane * 2];

  // dynamic node loop: each wave grabs the next unprocessed local node
  for (;;) {
    int idx;
    if (lane == 0) idx = atomicAdd(&nextn, 1);
    idx = __shfl(idx, 0);
    if (idx >= 32) break;
    const int c = row0 + idx;
    ushort2 o = make_ushort2(0, 0);
    if (c < n) {
      const int begin = (c == 0) ? 0 : P[c - 1];
      const int end = P[c];
      uint s = *(const uint*)&xws[(size_t)c * 128 + off];  // self term
      float ax = b2f_lo(s), ay = b2f_hi(s);
      int e = begin;
      for (; e + 4 <= end; e += 4) {
        int r0 = srcrow[e], r1 = srcrow[e + 1], r2 = srcrow[e + 2], r3 = srcrow[e + 3];
        uint v0 = *(const uint*)&xws[(size_t)r0 * 128 + off];
        uint v1 = *(const uint*)&xws[(size_t)r1 * 128 + off];
        uint v2 = *(const uint*)&xws[(size_t)r2 * 128 + off];
        uint v3 = *(const uint*)&xws[(size_t)r3 * 128 + off];
        ax += (b2f_lo(v0) + b2f_lo(v1)) + (b2f_lo(v2) + b2f_lo(v3));
        ay += (b2f_hi(v0) + b2f_hi(v1)) + (b2f_hi(v2) + b2f_hi(v3));
      }
      for (; e < end; ++e) {
        uint v = *(const uint*)&xws[(size_t)srcrow[e] * 128 + off];
        ax += b2f_lo(v);
        ay += b2f_hi(v);
      }
      const float dc = dinv[c];
      o.x = f2b(fmaxf(fmaf(dc, ax, bg.x), 0.f));
      o.y = f2b(fmaxf(fmaf(dc, ay, bg.y), 0.f));
    }
    *(ushort2*)&ts[idx][off] = o;
  }
  __syncthreads();

  // out = ts @ Wtc^T + bc : 2 row-blocks x 3 col-blocks = 6 MFMA tiles
  if (wid < 6) {
    const int rb = wid & 1, nb = wid >> 1;
    const int fr = lane & 15, fg = lane >> 4;
    f32x4 acc = (f32x4){0.f, 0.f, 0.f, 0.f};
#pragma unroll
    for (int ks = 0; ks < 4; ++ks) {
      const int kb = ks * 32 + fg * 8;
      bf16x8 a = *(const bf16x8*)&ts[rb * 16 + fr][kb];
      bf16x8 b = *(const bf16x8*)&Bs[nb * 16 + fr][kb];
      acc = __builtin_amdgcn_mfma_f32_16x16x32_bf16(a, b, acc, 0, 0, 0);
    }
    const int cn = nb * 16 + fr;
    if (cn < 40) {
      const float bv = bc[cn];
      const int r0 = row0 + rb * 16 + fg * 4;
#pragma unroll
      for (int i = 0; i < 4; ++i) {
        const int rr = r0 + i;
        if (rr < n) out[(size_t)rr * 40 + cn] = acc[i] + bv;
      }
    }
  }
}

extern "C" void kernel_launch(void* const* d_in, const int* in_sizes, int n_in,
                              void* d_out, int out_size, void* d_ws, size_t ws_size,
                              hipStream_t stream) {
  const float* x     = (const float*)d_in[0];
  const int*   ei    = (const int*)d_in[1];
  const float* W_in  = (const float*)d_in[2];
  const float* b_in  = (const float*)d_in[3];
  const float* W_gcn = (const float*)d_in[4];
  const float* b_gcn = (const float*)d_in[5];
  const float* W_cls = (const float*)d_in[6];
  const float* b_cls = (const float*)d_in[7];
  float* out = (float*)d_out;

  const int N = in_sizes[0] / 128;
  const int E = in_sizes[1] / 2;
  const int* row = ei;
  const int* col = ei + E;

  const int sortb = (E + CH_MAX - 1) / CH_MAX;   // 128 for E=600000
  const int chunk = (E + sortb - 1) / sortb;      // <= CH_MAX
  const int nbuck = (N + 127) >> 7;               // 391

  // d_ws layout (~18.3 MB): xws, weights, sort scratch, CSR
  ushort* xws    = (ushort*)d_ws;                 // N*128 bf16
  ushort* Wti    = xws + (size_t)N * 128;         // 128x128
  ushort* Wtg    = Wti + 128 * 128;               // 128x128
  ushort* Wtc    = Wtg + 128 * 128;               // 48x128 zero-padded
  uint*   ebuf   = (uint*)(Wtc + 48 * 128);       // E
  int*    srcrow = (int*)(ebuf + E);              // E
  int*    H2     = srcrow + E;                    // NBUCK*sortb
  int*    Hs     = H2 + NBUCK * sortb;            // NBUCK+1
  int*    cursor = Hs + NBUCK + 1;                // NBUCK
  int*    P      = cursor + NBUCK;                // N
  float*  dinv   = (float*)(P + N);               // N

  // weight prep + per-chunk coarse histogram (fused)
  k_prep_chist<<<PREP_BLKS + sortb, 256, 0, stream>>>(W_in, W_gcn, W_cls,
                                                      Wti, Wtg, Wtc,
                                                      col, H2, E, chunk, sortb);
  // reduce+scan 512 buckets, zero cursors
  k_scanH<<<1, 256, 0, stream>>>(H2, Hs, cursor, sortb);
  // pack edges by bucket (in-bucket order arbitrary)
  k_reorder<<<sortb, 256, 0, stream>>>(row, col, Hs, cursor, ebuf, E, chunk);
  // per-bucket fine sort -> srcrow CSR + P + dinv
  k_sort2<<<nbuck, 256, 0, stream>>>(ebuf, Hs, srcrow, P, dinv, N);

  // xws = dinv[r] * (relu(x@W_in + b_in) @ W_gcn)
  k_gemm12<<<(N + 63) / 64, 256, 0, stream>>>(x, Wti, Wtg, b_in, dinv, xws, N);

  // out = relu(dinv[c]*(sum xws[r] + xws[c]) + b_gcn) @ W_cls + b_cls
  k_aggout<<<(N + 31) / 32, 512, 0, stream>>>(P, srcrow, xws, dinv, b_gcn,
                                              Wtc, b_cls, out, N);
}

// Round 9
// 98.182 us; speedup vs baseline: 6.1347x; 1.1788x over previous
//
#include <hip/hip_runtime.h>

// ---------------------------------------------------------------------------
// PYG_GCN: y = relu(x@W_in+b_in) -> GCNConv(W_gcn,b_gcn) -> relu -> @W_cls+b_cls
// N=50000, E=600000, D=128, C=40.
// R9: overlap independent stages via block-range-split launches:
//   L1 prep||chist, L2 scan||GEMM1, L3 reorder||GEMM2(unscaled),
//   L4 sort2+xws-row-scale, L5 aggout (unchanged R8).
// ---------------------------------------------------------------------------

typedef __bf16 bf16x8 __attribute__((ext_vector_type(8)));
typedef float f32x4 __attribute__((ext_vector_type(4)));

#define NBUCK 512      // bucket = col>>7; used 0..390 for N=50000
#define CH_MAX 4704    // max edges per sort-chunk block
#define PREP_BLKS 152  // 38912 weight elements / 256

__device__ __forceinline__ ushort f2b(float f) {  // fp32 -> bf16 RNE
  uint u = __float_as_uint(f);
  return (ushort)((u + 0x7FFFu + ((u >> 16) & 1u)) >> 16);
}
__device__ __forceinline__ float b2f_lo(uint u) { return __uint_as_float(u << 16); }
__device__ __forceinline__ float b2f_hi(uint u) { return __uint_as_float(u & 0xFFFF0000u); }

// ---------------- L1: weight prep (blocks 0..151) || coarse chist ----------
// H2 bucket-major: H2[b*sortb + chunk_blk] (pure stores, no zeroing).
__global__ __launch_bounds__(256) void k_prep_chist(const float* __restrict__ Wi,
                                                    const float* __restrict__ Wg,
                                                    const float* __restrict__ Wc,
                                                    ushort* __restrict__ Ti,
                                                    ushort* __restrict__ Tg,
                                                    ushort* __restrict__ Tc,
                                                    const int* __restrict__ col,
                                                    int* __restrict__ H2,
                                                    int E, int chunk, int sortb) {
  __shared__ int hist[NBUCK];
  const int tid = threadIdx.x;
  if (blockIdx.x < PREP_BLKS) {
    int idx = blockIdx.x * 256 + tid;
    if (idx < 16384) {
      int c = idx >> 7, k = idx & 127;
      Ti[c * 128 + k] = f2b(Wi[k * 128 + c]);
    } else if (idx < 32768) {
      int j = idx - 16384;
      int c = j >> 7, k = j & 127;
      Tg[c * 128 + k] = f2b(Wg[k * 128 + c]);
    } else if (idx < 38912) {
      int j = idx - 32768;
      int c = j >> 7, k = j & 127;
      Tc[c * 128 + k] = (c < 40) ? f2b(Wc[k * 40 + c]) : (ushort)0;
    }
    return;
  }
  const int blk = blockIdx.x - PREP_BLKS;
  for (int b = tid; b < NBUCK; b += 256) hist[b] = 0;
  __syncthreads();
  const int e0 = blk * chunk;
  const int cnt = min(chunk, E - e0);
  for (int i = tid; i < cnt; i += 256)
    atomicAdd(&hist[((unsigned)col[e0 + i]) >> 7], 1);
  __syncthreads();
  for (int b = tid; b < NBUCK; b += 256)
    H2[b * sortb + blk] = hist[b];
}

// ---------------- L2: block 0 = bucket scan; blocks 1.. = GEMM1 ------------
// GEMM1: h = relu(x @ W_in + b_in), 128-row tiles, 8 waves.
__global__ __launch_bounds__(512) void k_scan_gemm1(const int* __restrict__ H2,
                                                    int* __restrict__ Hs,
                                                    int* __restrict__ cursor,
                                                    int sortb,
                                                    const float* __restrict__ x,
                                                    const ushort* __restrict__ Wti,
                                                    const float* __restrict__ b_in,
                                                    ushort* __restrict__ h, int nrows) {
  __shared__ __align__(16) char smem[69632];
  const int tid = threadIdx.x;
  if (blockIdx.x == 0) {
    int* sd = (int*)smem;  // 512 ints
    int s = 0;
    const int4* p = (const int4*)&H2[tid * sortb];
    for (int j = 0; j < sortb / 4; ++j) { int4 v = p[j]; s += v.x + v.y + v.z + v.w; }
    sd[tid] = s;
    __syncthreads();
    for (int off = 1; off < 512; off <<= 1) {
      int u = (tid >= off) ? sd[tid - off] : 0;
      __syncthreads();
      sd[tid] += u;
      __syncthreads();
    }
    Hs[tid] = sd[tid] - s;          // exclusive
    if (tid == 511) Hs[NBUCK] = sd[511];
    cursor[tid] = 0;
    return;
  }
  ushort (*As)[136] = (ushort(*)[136])smem;                    // 128 rows
  ushort (*Bs)[136] = (ushort(*)[136])(smem + 128 * 136 * 2);  // 128 rows
  const int row0 = (blockIdx.x - 1) * 128;
#pragma unroll
  for (int q = 0; q < 4; ++q) {
    int f = tid + 512 * q;
    int r = f >> 4, cw = f & 15;
    *(uint4*)&Bs[r][cw * 8] = *(const uint4*)&Wti[r * 128 + cw * 8];
  }
#pragma unroll
  for (int q = 0; q < 8; ++q) {
    int f = tid + 512 * q;
    int r = f >> 5, kc = f & 31;
    float4 v = make_float4(0.f, 0.f, 0.f, 0.f);
    if (row0 + r < nrows) v = *(const float4*)&x[(size_t)(row0 + r) * 128 + kc * 4];
    ushort4 o;
    o.x = f2b(v.x); o.y = f2b(v.y); o.z = f2b(v.z); o.w = f2b(v.w);
    *(ushort4*)&As[r][kc * 4] = o;
  }
  __syncthreads();

  const int wid = tid >> 6, lane = tid & 63;
  const int fr = lane & 15, fg = lane >> 4;
  f32x4 acc[8];
#pragma unroll
  for (int n = 0; n < 8; ++n) acc[n] = (f32x4){0.f, 0.f, 0.f, 0.f};
#pragma unroll
  for (int ks = 0; ks < 4; ++ks) {
    const int kb = ks * 32 + fg * 8;
    bf16x8 a = *(const bf16x8*)&As[wid * 16 + fr][kb];
#pragma unroll
    for (int n = 0; n < 8; ++n) {
      bf16x8 b = *(const bf16x8*)&Bs[n * 16 + fr][kb];
      acc[n] = __builtin_amdgcn_mfma_f32_16x16x32_bf16(a, b, acc[n], 0, 0, 0);
    }
  }
  const int r0 = row0 + wid * 16 + fg * 4;
#pragma unroll
  for (int n = 0; n < 8; ++n) {
    const int cn = n * 16 + fr;
    const float bv = b_in[cn];
#pragma unroll
    for (int i = 0; i < 4; ++i) {
      const int rr = r0 + i;
      if (rr < nrows) h[(size_t)rr * 128 + cn] = f2b(fmaxf(acc[n][i] + bv, 0.f));
    }
  }
}

// ---------------- L3: blocks [0,sortb) = reorder; rest = GEMM2 -------------
// ebuf record: (c_local<<16) | row. GEMM2: xws = h @ W_gcn (UNSCALED).
__global__ __launch_bounds__(256) void k_reorder_gemm2(const int* __restrict__ row,
                                                       const int* __restrict__ col,
                                                       const int* __restrict__ Hs,
                                                       int* __restrict__ cursor,
                                                       uint* __restrict__ ebuf,
                                                       int E, int chunk, int sortb,
                                                       const ushort* __restrict__ h,
                                                       const ushort* __restrict__ Wtg,
                                                       ushort* __restrict__ xws,
                                                       int nrows) {
  __shared__ __align__(16) char smem[52224];
  const int tid = threadIdx.x;
  if (blockIdx.x < sortb) {
    int* hist   = (int*)smem;            // NBUCK
    int* lstart = hist + NBUCK;          // NBUCK
    int* cnt2   = lstart + NBUCK;        // NBUCK
    int* obase  = cnt2 + NBUCK;          // NBUCK
    uint* data  = (uint*)(obase + NBUCK);  // CH_MAX
    int* gpos   = (int*)(data + CH_MAX);   // CH_MAX
    int* sd     = gpos + CH_MAX;           // 256
    for (int b = tid; b < NBUCK; b += 256) { hist[b] = 0; cnt2[b] = 0; }
    __syncthreads();
    const int e0 = blockIdx.x * chunk;
    const int cnt = min(chunk, E - e0);
    for (int i = tid; i < cnt; i += 256)
      atomicAdd(&hist[((unsigned)col[e0 + i]) >> 7], 1);
    __syncthreads();
    const int h0 = hist[2 * tid], h1 = hist[2 * tid + 1];
    const int ps = h0 + h1;
    sd[tid] = ps;
    __syncthreads();
    for (int off = 1; off < 256; off <<= 1) {
      int u = (tid >= off) ? sd[tid - off] : 0;
      __syncthreads();
      sd[tid] += u;
      __syncthreads();
    }
    const int ex = sd[tid] - ps;
    lstart[2 * tid] = ex;
    lstart[2 * tid + 1] = ex + h0;
    obase[2 * tid]     = Hs[2 * tid]     + (h0 ? atomicAdd(&cursor[2 * tid], h0) : 0);
    obase[2 * tid + 1] = Hs[2 * tid + 1] + (h1 ? atomicAdd(&cursor[2 * tid + 1], h1) : 0);
    __syncthreads();
    for (int i = tid; i < cnt; i += 256) {
      const int c = col[e0 + i], r = row[e0 + i];
      const int b = ((unsigned)c) >> 7;
      const int rk = atomicAdd(&cnt2[b], 1);
      const int slot = lstart[b] + rk;
      data[slot] = ((uint)(c & 127) << 16) | (uint)r;
      gpos[slot] = obase[b] + rk;
    }
    __syncthreads();
    for (int i = tid; i < cnt; i += 256)
      ebuf[gpos[i]] = data[i];
    return;
  }
  // GEMM2: 64-row tile, 4 waves
  ushort (*As)[136] = (ushort(*)[136])smem;                   // 64 rows
  ushort (*Bs)[136] = (ushort(*)[136])(smem + 64 * 136 * 2);  // 128 rows
  const int row0 = (blockIdx.x - sortb) * 64;
#pragma unroll
  for (int q = 0; q < 8; ++q) {
    int f = tid + 256 * q;
    int r = f >> 4, cw = f & 15;
    *(uint4*)&Bs[r][cw * 8] = *(const uint4*)&Wtg[r * 128 + cw * 8];
  }
#pragma unroll
  for (int q = 0; q < 4; ++q) {
    int f = tid + 256 * q;
    int r = f >> 4, cw = f & 15;
    uint4 v = make_uint4(0u, 0u, 0u, 0u);
    if (row0 + r < nrows) v = *(const uint4*)&h[(size_t)(row0 + r) * 128 + cw * 8];
    *(uint4*)&As[r][cw * 8] = v;
  }
  __syncthreads();
  const int wid = tid >> 6, lane = tid & 63;
  const int fr = lane & 15, fg = lane >> 4;
  f32x4 acc[8];
#pragma unroll
  for (int n = 0; n < 8; ++n) acc[n] = (f32x4){0.f, 0.f, 0.f, 0.f};
#pragma unroll
  for (int ks = 0; ks < 4; ++ks) {
    const int kb = ks * 32 + fg * 8;
    bf16x8 a = *(const bf16x8*)&As[wid * 16 + fr][kb];
#pragma unroll
    for (int n = 0; n < 8; ++n) {
      bf16x8 b = *(const bf16x8*)&Bs[n * 16 + fr][kb];
      acc[n] = __builtin_amdgcn_mfma_f32_16x16x32_bf16(a, b, acc[n], 0, 0, 0);
    }
  }
  const int r0 = row0 + wid * 16 + fg * 4;
#pragma unroll
  for (int n = 0; n < 8; ++n) {
    const int cn = n * 16 + fr;
#pragma unroll
    for (int i = 0; i < 4; ++i) {
      const int rr = r0 + i;
      if (rr < nrows) xws[(size_t)rr * 128 + cn] = f2b(acc[n][i]);
    }
  }
}

// ---------------- L4: per-bucket fine sort + P + dinv + xws row-scale ------
// P[node] = END offset (seg = [P[c-1], P[c])). xws[row] *= dinv[row].
__global__ __launch_bounds__(256) void k_sort2s(const uint* __restrict__ ebuf,
                                                const int* __restrict__ Hs,
                                                int* __restrict__ srcrow,
                                                int* __restrict__ P,
                                                float* __restrict__ dinv,
                                                ushort* __restrict__ xws,
                                                int n) {
  __shared__ int cnt[128];
  __shared__ int lstart[128];
  __shared__ int cnt2[128];
  __shared__ int sd[256];
  __shared__ float dvs[128];
  const int tid = threadIdx.x;
  if (tid < 128) { cnt[tid] = 0; cnt2[tid] = 0; }
  __syncthreads();
  const int b = blockIdx.x;
  const int start = Hs[b];
  const int end = Hs[b + 1];
  for (int i = start + tid; i < end; i += 256)
    atomicAdd(&cnt[ebuf[i] >> 16], 1);
  __syncthreads();
  const int cv = (tid < 128) ? cnt[tid] : 0;
  sd[tid] = cv;
  __syncthreads();
  for (int off = 1; off < 256; off <<= 1) {
    int u = (tid >= off) ? sd[tid - off] : 0;
    __syncthreads();
    sd[tid] += u;
    __syncthreads();
  }
  if (tid < 128) {
    const int ex = sd[tid] - cv;
    lstart[tid] = ex;
    const float dv = rsqrtf((float)cv + 1.0f);
    dvs[tid] = dv;
    const int node = b * 128 + tid;
    if (node < n) {
      P[node] = start + ex + cv;
      dinv[node] = dv;
    }
  }
  __syncthreads();
  // scale this bucket's 128 xws rows by dinv[row] (coalesced, 32KB)
  for (int j = tid; j < 128 * 16; j += 256) {
    const int rl = j >> 4, c8 = j & 15;
    const int node = b * 128 + rl;
    if (node < n) {
      const float dv = dvs[rl];
      uint4 v = *(const uint4*)&xws[(size_t)node * 128 + c8 * 8];
      uint o0 = ((uint)f2b(b2f_hi(v.x) * dv) << 16) | f2b(b2f_lo(v.x) * dv);
      uint o1 = ((uint)f2b(b2f_hi(v.y) * dv) << 16) | f2b(b2f_lo(v.y) * dv);
      uint o2 = ((uint)f2b(b2f_hi(v.z) * dv) << 16) | f2b(b2f_lo(v.z) * dv);
      uint o3 = ((uint)f2b(b2f_hi(v.w) * dv) << 16) | f2b(b2f_lo(v.w) * dv);
      *(uint4*)&xws[(size_t)node * 128 + c8 * 8] = make_uint4(o0, o1, o2, o3);
    }
  }
  // scatter srcrow within the bucket's private window
  for (int i = start + tid; i < end; i += 256) {
    const uint v = ebuf[i];
    const int c = v >> 16;
    const int rk = atomicAdd(&cnt2[c], 1);
    srcrow[start + lstart[c] + rk] = (int)(v & 0xFFFFu);
  }
}

// ---------------- L5: fused aggregate + classifier (R8, unchanged) ---------
__global__ __launch_bounds__(512) void k_aggout(const int* __restrict__ P,
                                                const int* __restrict__ srcrow,
                                                const ushort* __restrict__ xws,
                                                const float* __restrict__ dinv,
                                                const float* __restrict__ b_gcn,
                                                const ushort* __restrict__ Wtc,
                                                const float* __restrict__ bc,
                                                float* __restrict__ out, int n) {
  __shared__ ushort ts[32][136];
  __shared__ ushort Bs[48][136];
  __shared__ int nextn;
  const int tid = threadIdx.x;
#pragma unroll
  for (int q = 0; q < 2; ++q) {
    int f = tid + 512 * q;
    if (f < 768) {
      int r = f >> 4, cw = f & 15;
      *(uint4*)&Bs[r][cw * 8] = *(const uint4*)&Wtc[r * 128 + cw * 8];
    }
  }
  if (tid == 0) nextn = 0;
  __syncthreads();

  const int wid = tid >> 6, lane = tid & 63;
  const int row0 = blockIdx.x * 32;
  const size_t off = (size_t)lane * 2;
  const float2 bg = *(const float2*)&b_gcn[lane * 2];

  for (;;) {
    int idx;
    if (lane == 0) idx = atomicAdd(&nextn, 1);
    idx = __shfl(idx, 0);
    if (idx >= 32) break;
    const int c = row0 + idx;
    ushort2 o = make_ushort2(0, 0);
    if (c < n) {
      const int begin = (c == 0) ? 0 : P[c - 1];
      const int end = P[c];
      uint s = *(const uint*)&xws[(size_t)c * 128 + off];  // self term (pre-scaled)
      float ax = b2f_lo(s), ay = b2f_hi(s);
      int e = begin;
      for (; e + 4 <= end; e += 4) {
        int r0 = srcrow[e], r1 = srcrow[e + 1], r2 = srcrow[e + 2], r3 = srcrow[e + 3];
        uint v0 = *(const uint*)&xws[(size_t)r0 * 128 + off];
        uint v1 = *(const uint*)&xws[(size_t)r1 * 128 + off];
        uint v2 = *(const uint*)&xws[(size_t)r2 * 128 + off];
        uint v3 = *(const uint*)&xws[(size_t)r3 * 128 + off];
        ax += (b2f_lo(v0) + b2f_lo(v1)) + (b2f_lo(v2) + b2f_lo(v3));
        ay += (b2f_hi(v0) + b2f_hi(v1)) + (b2f_hi(v2) + b2f_hi(v3));
      }
      for (; e < end; ++e) {
        uint v = *(const uint*)&xws[(size_t)srcrow[e] * 128 + off];
        ax += b2f_lo(v);
        ay += b2f_hi(v);
      }
      const float dc = dinv[c];
      o.x = f2b(fmaxf(fmaf(dc, ax, bg.x), 0.f));
      o.y = f2b(fmaxf(fmaf(dc, ay, bg.y), 0.f));
    }
    *(ushort2*)&ts[idx][off] = o;
  }
  __syncthreads();

  if (wid < 6) {
    const int rb = wid & 1, nb = wid >> 1;
    const int fr = lane & 15, fg = lane >> 4;
    f32x4 acc = (f32x4){0.f, 0.f, 0.f, 0.f};
#pragma unroll
    for (int ks = 0; ks < 4; ++ks) {
      const int kb = ks * 32 + fg * 8;
      bf16x8 a = *(const bf16x8*)&ts[rb * 16 + fr][kb];
      bf16x8 b = *(const bf16x8*)&Bs[nb * 16 + fr][kb];
      acc = __builtin_amdgcn_mfma_f32_16x16x32_bf16(a, b, acc, 0, 0, 0);
    }
    const int cn = nb * 16 + fr;
    if (cn < 40) {
      const float bv = bc[cn];
      const int r0 = row0 + rb * 16 + fg * 4;
#pragma unroll
      for (int i = 0; i < 4; ++i) {
        const int rr = r0 + i;
        if (rr < n) out[(size_t)rr * 40 + cn] = acc[i] + bv;
      }
    }
  }
}

extern "C" void kernel_launch(void* const* d_in, const int* in_sizes, int n_in,
                              void* d_out, int out_size, void* d_ws, size_t ws_size,
                              hipStream_t stream) {
  const float* x     = (const float*)d_in[0];
  const int*   ei    = (const int*)d_in[1];
  const float* W_in  = (const float*)d_in[2];
  const float* b_in  = (const float*)d_in[3];
  const float* W_gcn = (const float*)d_in[4];
  const float* b_gcn = (const float*)d_in[5];
  const float* W_cls = (const float*)d_in[6];
  const float* b_cls = (const float*)d_in[7];
  float* out = (float*)d_out;

  const int N = in_sizes[0] / 128;
  const int E = in_sizes[1] / 2;
  const int* row = ei;
  const int* col = ei + E;

  const int sortb = (E + CH_MAX - 1) / CH_MAX;   // 128 for E=600000
  const int chunk = (E + sortb - 1) / sortb;      // <= CH_MAX
  const int nbuck = (N + 127) >> 7;               // 391

  // d_ws layout (~31 MB)
  ushort* h      = (ushort*)d_ws;                 // N*128 bf16
  ushort* xws    = h + (size_t)N * 128;           // N*128 bf16
  ushort* Wti    = xws + (size_t)N * 128;         // 128x128
  ushort* Wtg    = Wti + 128 * 128;               // 128x128
  ushort* Wtc    = Wtg + 128 * 128;               // 48x128 zero-padded
  uint*   ebuf   = (uint*)(Wtc + 48 * 128);       // E
  int*    srcrow = (int*)(ebuf + E);              // E
  int*    H2     = srcrow + E;                    // NBUCK*sortb
  int*    Hs     = H2 + NBUCK * sortb;            // NBUCK+1
  int*    cursor = Hs + NBUCK + 1;                // NBUCK
  int*    P      = cursor + NBUCK;                // N
  float*  dinv   = (float*)(P + N);               // N

  // L1: weight prep || coarse chist
  k_prep_chist<<<PREP_BLKS + sortb, 256, 0, stream>>>(W_in, W_gcn, W_cls,
                                                      Wti, Wtg, Wtc,
                                                      col, H2, E, chunk, sortb);
  // L2: bucket scan || GEMM1 (h = relu(x@W_in+b_in))
  k_scan_gemm1<<<1 + (N + 127) / 128, 512, 0, stream>>>(H2, Hs, cursor, sortb,
                                                        x, Wti, b_in, h, N);
  // L3: reorder || GEMM2 (xws = h@W_gcn, unscaled)
  k_reorder_gemm2<<<sortb + (N + 63) / 64, 256, 0, stream>>>(row, col, Hs, cursor,
                                                             ebuf, E, chunk, sortb,
                                                             h, Wtg, xws, N);
  // L4: fine sort -> srcrow/P/dinv + scale xws rows by dinv[r]
  k_sort2s<<<nbuck, 256, 0, stream>>>(ebuf, Hs, srcrow, P, dinv, xws, N);

  // L5: out = relu(dinv[c]*(sum xws[r] + xws[c]) + b_gcn) @ W_cls + b_cls
  k_aggout<<<(N + 31) / 32, 512, 0, stream>>>(P, srcrow, xws, dinv, b_gcn,
                                              Wtc, b_cls, out, N);
}